// Round 8
// baseline (221605.029 us; speedup 1.0000x reference)
//
#include <hip/hip_runtime.h>
#include <math.h>

#define LAYERS 8
#define C 384
#define NH 8
#define NE 4
#define TD 256
#define NV 256
#define WIN 64
#define MM 56
#define HD 48
#define BB 64
#define TT 256
#define NT (BB*TT)
#define N3C 1152
#define FF 1536
#define KV 312
#define FCH 384              // MoE FF chunk width
#define SCALE_QK 0.14433756729740643f

static __device__ __forceinline__ float wsum(float v){
#pragma unroll
  for(int o=32;o;o>>=1) v += __shfl_xor(v,o);
  return v;
}

// ---------------- embed ----------------
__global__ void k_embed(const int* __restrict__ tokens, const float* __restrict__ tok_emb,
                        const float* __restrict__ pos_emb, float* __restrict__ x){
  int idx = blockIdx.x*256 + threadIdx.x;
  if (idx >= NT*C) return;
  int t = idx / C, c = idx - t*C;
  x[idx] = tok_emb[tokens[t]*C + c] + pos_emb[(t % TT)*C + c];
}

// ---------------- layernorm (wave per row) ----------------
__global__ void k_ln(const float* __restrict__ in, const float* __restrict__ w,
                     const float* __restrict__ b, float* __restrict__ out){
  int row = blockIdx.x*4 + (threadIdx.x>>6);
  int lane = threadIdx.x & 63;
  const float* xr = in + (size_t)row*C;
  float v[6]; float s = 0.f;
#pragma unroll
  for(int i=0;i<6;i++){ v[i]=xr[lane+64*i]; s+=v[i]; }
  s = wsum(s);
  float mu = s*(1.f/C);
  float q=0.f;
#pragma unroll
  for(int i=0;i<6;i++){ float d=v[i]-mu; q+=d*d; }
  q = wsum(q);
  float inv = rsqrtf(q*(1.f/C)+1e-5f);
  float* orow = out + (size_t)row*C;
#pragma unroll
  for(int i=0;i<6;i++){ int c=lane+64*i; orow[c] = (v[i]-mu)*inv*w[c]+b[c]; }
}

// ---------------- GEMM 128x128, BK=32, single LDS buffer, 8x8/thread ----------------
// Schedule per tile: barrier -> issue next-tile globals -> 32kk compute -> barrier -> ds_write.
// ACT: 0 none, 1 tanh, 2 gelu. MOE: z=expert; GATHER: A rows via ridx.
template<int ACT, bool ACCUM, bool MOE, bool GATHER>
__global__ __launch_bounds__(256,4) void k_gemm128(
    const float* __restrict__ A, const float* __restrict__ W,
    const float* __restrict__ bias,
    const int* __restrict__ ridx, const int* __restrict__ cnt,
    size_t sWz, size_t sBz,
    float* __restrict__ Cout, int Kn, int ldA, int ldB, int ldC)
{
  const int z = MOE ? (int)blockIdx.z : 0;
  int Mn = NT;
  if (MOE){
    int eb = 0;
#pragma unroll
    for(int i=0;i<NE;i++){ int ci = cnt[i]; if (i<z) eb += ci; if (i==z) Mn = ci; }
    W += (size_t)z*sWz;
    if (bias) bias += (size_t)z*sBz;
    if (!GATHER) A += (size_t)eb*ldA;
    Cout += (size_t)eb*ldC;
  }
  const int bm = (int)blockIdx.y<<7, bn = (int)blockIdx.x<<7;
  if (bm >= Mn) return;
  __shared__ __attribute__((aligned(16))) float As[32][132];
  __shared__ __attribute__((aligned(16))) float Bs[32][132];
  const int tid = threadIdx.x;
  const int tx = tid&15, ty = tid>>4;
  const int arow = tid>>1, ak = (tid&1)<<4;   // A: 2 thr/row, 16-k half each
  const int brow = tid>>3, bc = (tid&7)<<4;   // B: 8 thr/row, 16 cols each
  int r0 = bm + arow; if (r0 >= Mn) r0 = Mn-1;
  const int agr = GATHER ? ridx[(size_t)z*NT + r0] : r0;
  const float* Arow = A + (size_t)agr*ldA + ak;
  const float* Wrow = W + (size_t)brow*ldB + bn + bc;
  float4 a0 = *(const float4*)(Arow);
  float4 a1 = *(const float4*)(Arow+4);
  float4 a2 = *(const float4*)(Arow+8);
  float4 a3 = *(const float4*)(Arow+12);
  float4 b0 = *(const float4*)(Wrow);
  float4 b1 = *(const float4*)(Wrow+4);
  float4 b2 = *(const float4*)(Wrow+8);
  float4 b3 = *(const float4*)(Wrow+12);
  // stage tile 0
  {
    As[ak+ 0][arow]=a0.x; As[ak+ 1][arow]=a0.y; As[ak+ 2][arow]=a0.z; As[ak+ 3][arow]=a0.w;
    As[ak+ 4][arow]=a1.x; As[ak+ 5][arow]=a1.y; As[ak+ 6][arow]=a1.z; As[ak+ 7][arow]=a1.w;
    As[ak+ 8][arow]=a2.x; As[ak+ 9][arow]=a2.y; As[ak+10][arow]=a2.z; As[ak+11][arow]=a2.w;
    As[ak+12][arow]=a3.x; As[ak+13][arow]=a3.y; As[ak+14][arow]=a3.z; As[ak+15][arow]=a3.w;
    *(float4*)&Bs[brow][bc]    = b0;
    *(float4*)&Bs[brow][bc+4]  = b1;
    *(float4*)&Bs[brow][bc+8]  = b2;
    *(float4*)&Bs[brow][bc+12] = b3;
  }
  float acc[8][8] = {};
  const int T = Kn>>5;
  for (int t=0; t<T; t++){
    __syncthreads();                      // staged tile visible
    const bool more = (t+1 < T);
    if (more){
      const int k1 = (t+1)<<5;
      a0 = *(const float4*)(Arow + k1);
      a1 = *(const float4*)(Arow + k1 + 4);
      a2 = *(const float4*)(Arow + k1 + 8);
      a3 = *(const float4*)(Arow + k1 + 12);
      const float* wr = Wrow + (size_t)k1*ldB;
      b0 = *(const float4*)(wr);
      b1 = *(const float4*)(wr+4);
      b2 = *(const float4*)(wr+8);
      b3 = *(const float4*)(wr+12);
    }
#pragma unroll
    for (int kk=0;kk<32;kk++){
      float av[8], bv[8];
      *(float4*)&av[0] = *(const float4*)&As[kk][ty<<3];
      *(float4*)&av[4] = *(const float4*)&As[kk][(ty<<3)+4];
      *(float4*)&bv[0] = *(const float4*)&Bs[kk][tx<<2];
      *(float4*)&bv[4] = *(const float4*)&Bs[kk][64+(tx<<2)];
#pragma unroll
      for(int i=0;i<8;i++)
#pragma unroll
        for(int j=0;j<8;j++) acc[i][j] += av[i]*bv[j];
    }
    __syncthreads();                      // compute done
    if (more){
      As[ak+ 0][arow]=a0.x; As[ak+ 1][arow]=a0.y; As[ak+ 2][arow]=a0.z; As[ak+ 3][arow]=a0.w;
      As[ak+ 4][arow]=a1.x; As[ak+ 5][arow]=a1.y; As[ak+ 6][arow]=a1.z; As[ak+ 7][arow]=a1.w;
      As[ak+ 8][arow]=a2.x; As[ak+ 9][arow]=a2.y; As[ak+10][arow]=a2.z; As[ak+11][arow]=a2.w;
      As[ak+12][arow]=a3.x; As[ak+13][arow]=a3.y; As[ak+14][arow]=a3.z; As[ak+15][arow]=a3.w;
      *(float4*)&Bs[brow][bc]    = b0;
      *(float4*)&Bs[brow][bc+4]  = b1;
      *(float4*)&Bs[brow][bc+8]  = b2;
      *(float4*)&Bs[brow][bc+12] = b3;
    }
  }
  const int c0 = bn + (tx<<2), c1 = c0 + 64;
  float4 bias0 = make_float4(0,0,0,0), bias1 = make_float4(0,0,0,0);
  if (bias){ bias0 = *(const float4*)&bias[c0]; bias1 = *(const float4*)&bias[c1]; }
#pragma unroll
  for(int i=0;i<8;i++){
    const int row = bm + (ty<<3) + i;
    if (row < Mn){
      float v[8];
      v[0]=acc[i][0]+bias0.x; v[1]=acc[i][1]+bias0.y; v[2]=acc[i][2]+bias0.z; v[3]=acc[i][3]+bias0.w;
      v[4]=acc[i][4]+bias1.x; v[5]=acc[i][5]+bias1.y; v[6]=acc[i][6]+bias1.z; v[7]=acc[i][7]+bias1.w;
#pragma unroll
      for(int j=0;j<8;j++){
        if (ACT==1) v[j] = tanhf(v[j]);
        if (ACT==2) v[j] = 0.5f*v[j]*(1.0f+erff(v[j]*0.70710678118654752f));
      }
      float* p0 = Cout + (size_t)row*ldC + c0;
      float* p1 = Cout + (size_t)row*ldC + c1;
      float4 w0 = make_float4(v[0],v[1],v[2],v[3]);
      float4 w1 = make_float4(v[4],v[5],v[6],v[7]);
      if (ACCUM){
        float4 o0 = *(const float4*)p0, o1 = *(const float4*)p1;
        w0.x+=o0.x; w0.y+=o0.y; w0.z+=o0.z; w0.w+=o0.w;
        w1.x+=o1.x; w1.y+=o1.y; w1.z+=o1.z; w1.w+=o1.w;
      }
      *(float4*)p0 = w0;
      *(float4*)p1 = w1;
    }
  }
}

// ---------------- GEMM 64x128, BK=32, single LDS buffer, 4x8/thread ----------------
// For small-N GEMMs: doubles the grid (M/64 blocks) for CU co-residency.
template<int ACT, bool ACCUM, bool MOE>
__global__ __launch_bounds__(256,4) void k_gemm64(
    const float* __restrict__ A, const float* __restrict__ W,
    const float* __restrict__ bias,
    const int* __restrict__ cnt,
    size_t sWz, size_t sBz,
    float* __restrict__ Cout, int Kn, int ldA, int ldB, int ldC)
{
  const int z = MOE ? (int)blockIdx.z : 0;
  int Mn = NT;
  if (MOE){
    int eb = 0;
#pragma unroll
    for(int i=0;i<NE;i++){ int ci = cnt[i]; if (i<z) eb += ci; if (i==z) Mn = ci; }
    W += (size_t)z*sWz;
    if (bias) bias += (size_t)z*sBz;
    A += (size_t)eb*ldA;
    Cout += (size_t)eb*ldC;
  }
  const int bm = (int)blockIdx.y<<6, bn = (int)blockIdx.x<<7;
  if (bm >= Mn) return;
  __shared__ __attribute__((aligned(16))) float As[32][68];
  __shared__ __attribute__((aligned(16))) float Bs[32][132];
  const int tid = threadIdx.x;
  const int tx = tid&15, ty = tid>>4;
  const int arow = tid>>2, ak = (tid&3)<<3;   // A: 4 thr/row, 8-k each
  const int brow = tid>>3, bc = (tid&7)<<4;   // B: 8 thr/row, 16 cols each
  int r0 = bm + arow; if (r0 >= Mn) r0 = Mn-1;
  const float* Arow = A + (size_t)r0*ldA + ak;
  const float* Wrow = W + (size_t)brow*ldB + bn + bc;
  float4 a0 = *(const float4*)(Arow);
  float4 a1 = *(const float4*)(Arow+4);
  float4 b0 = *(const float4*)(Wrow);
  float4 b1 = *(const float4*)(Wrow+4);
  float4 b2 = *(const float4*)(Wrow+8);
  float4 b3 = *(const float4*)(Wrow+12);
  {
    As[ak+0][arow]=a0.x; As[ak+1][arow]=a0.y; As[ak+2][arow]=a0.z; As[ak+3][arow]=a0.w;
    As[ak+4][arow]=a1.x; As[ak+5][arow]=a1.y; As[ak+6][arow]=a1.z; As[ak+7][arow]=a1.w;
    *(float4*)&Bs[brow][bc]    = b0;
    *(float4*)&Bs[brow][bc+4]  = b1;
    *(float4*)&Bs[brow][bc+8]  = b2;
    *(float4*)&Bs[brow][bc+12] = b3;
  }
  float acc[4][8] = {};
  const int T = Kn>>5;
  for (int t=0; t<T; t++){
    __syncthreads();
    const bool more = (t+1 < T);
    if (more){
      const int k1 = (t+1)<<5;
      a0 = *(const float4*)(Arow + k1);
      a1 = *(const float4*)(Arow + k1 + 4);
      const float* wr = Wrow + (size_t)k1*ldB;
      b0 = *(const float4*)(wr);
      b1 = *(const float4*)(wr+4);
      b2 = *(const float4*)(wr+8);
      b3 = *(const float4*)(wr+12);
    }
#pragma unroll
    for (int kk=0;kk<32;kk++){
      float av[4], bv[8];
      *(float4*)&av[0] = *(const float4*)&As[kk][ty<<2];
      *(float4*)&bv[0] = *(const float4*)&Bs[kk][tx<<2];
      *(float4*)&bv[4] = *(const float4*)&Bs[kk][64+(tx<<2)];
#pragma unroll
      for(int i=0;i<4;i++)
#pragma unroll
        for(int j=0;j<8;j++) acc[i][j] += av[i]*bv[j];
    }
    __syncthreads();
    if (more){
      As[ak+0][arow]=a0.x; As[ak+1][arow]=a0.y; As[ak+2][arow]=a0.z; As[ak+3][arow]=a0.w;
      As[ak+4][arow]=a1.x; As[ak+5][arow]=a1.y; As[ak+6][arow]=a1.z; As[ak+7][arow]=a1.w;
      *(float4*)&Bs[brow][bc]    = b0;
      *(float4*)&Bs[brow][bc+4]  = b1;
      *(float4*)&Bs[brow][bc+8]  = b2;
      *(float4*)&Bs[brow][bc+12] = b3;
    }
  }
  const int c0 = bn + (tx<<2), c1 = c0 + 64;
  float4 bias0 = make_float4(0,0,0,0), bias1 = make_float4(0,0,0,0);
  if (bias){ bias0 = *(const float4*)&bias[c0]; bias1 = *(const float4*)&bias[c1]; }
#pragma unroll
  for(int i=0;i<4;i++){
    const int row = bm + (ty<<2) + i;
    if (row < Mn){
      float v[8];
      v[0]=acc[i][0]+bias0.x; v[1]=acc[i][1]+bias0.y; v[2]=acc[i][2]+bias0.z; v[3]=acc[i][3]+bias0.w;
      v[4]=acc[i][4]+bias1.x; v[5]=acc[i][5]+bias1.y; v[6]=acc[i][6]+bias1.z; v[7]=acc[i][7]+bias1.w;
#pragma unroll
      for(int j=0;j<8;j++){
        if (ACT==1) v[j] = tanhf(v[j]);
        if (ACT==2) v[j] = 0.5f*v[j]*(1.0f+erff(v[j]*0.70710678118654752f));
      }
      float* p0 = Cout + (size_t)row*ldC + c0;
      float* p1 = Cout + (size_t)row*ldC + c1;
      float4 w0 = make_float4(v[0],v[1],v[2],v[3]);
      float4 w1 = make_float4(v[4],v[5],v[6],v[7]);
      if (ACCUM){
        float4 o0 = *(const float4*)p0, o1 = *(const float4*)p1;
        w0.x+=o0.x; w0.y+=o0.y; w0.z+=o0.z; w0.w+=o0.w;
        w1.x+=o1.x; w1.y+=o1.y; w1.z+=o1.z; w1.w+=o1.w;
      }
      *(float4*)p0 = w0;
      *(float4*)p1 = w1;
    }
  }
}

// ---------------- attention: block per (b,head); lane-per-query 1-pass flash ----------------
__global__ __launch_bounds__(256) void k_attn(const float* __restrict__ qkv,
    const float* __restrict__ mem, const float* __restrict__ gate,
    float* __restrict__ y){
  __shared__ float ks[KV*50];
  __shared__ float vs[KV*50];
  const int b = blockIdx.x >> 3, hh = blockIdx.x & 7;
  const int tid = threadIdx.x;
  for(int idx=tid; idx<KV*24; idx+=256){
    int j = idx/24, f = (idx - j*24)*2;
    float2 kvv, vvv;
    if (j < MM){
      kvv = *(const float2*)(mem + j*C + hh*HD + f);
      vvv = kvv;
    } else {
      const float* row = qkv + (size_t)(b*TT + j - MM)*N3C + hh*HD + f;
      kvv = *(const float2*)(row + C);
      vvv = *(const float2*)(row + 2*C);
    }
    *(float2*)(ks + j*50 + f) = kvv;
    *(float2*)(vs + j*50 + f) = vvv;
  }
  __syncthreads();
  const int i = tid;
  const float* qrow = qkv + (size_t)(b*TT+i)*N3C + hh*HD;
  float q[HD];
#pragma unroll
  for(int d2=0; d2<24; d2++){
    float2 qv = *(const float2*)(qrow + d2*2);
    q[d2*2] = qv.x; q[d2*2+1] = qv.y;
  }
  float m = -1e30f, l = 0.f;
  float acc[HD];
#pragma unroll
  for(int d=0;d<HD;d++) acc[d]=0.f;

#define ATT_STEP(JROW) {                                            \
    const float* kr = ks + (JROW)*50;                               \
    float dot = 0.f;                                                \
    _Pragma("unroll")                                               \
    for(int d2=0; d2<24; d2++){                                     \
      float2 kv2 = *(const float2*)(kr + d2*2);                     \
      dot += q[d2*2]*kv2.x + q[d2*2+1]*kv2.y;                       \
    }                                                               \
    float s = dot*SCALE_QK;                                         \
    if (s > m + 8.f){                                               \
      float f_ = __expf(m - s);                                     \
      l *= f_;                                                      \
      _Pragma("unroll")                                             \
      for(int d=0; d<HD; d++) acc[d] *= f_;                         \
      m = s;                                                        \
    }                                                               \
    float pch = __expf(s - m);                                      \
    l += pch;                                                       \
    const float* vr = vs + (JROW)*50;                               \
    _Pragma("unroll")                                               \
    for(int d2=0; d2<24; d2++){                                     \
      float2 vv2 = *(const float2*)(vr + d2*2);                     \
      acc[d2*2]   += pch*vv2.x;                                     \
      acc[d2*2+1] += pch*vv2.y;                                     \
    }                                                               \
  }

  for(int j=0; j<MM; j++) ATT_STEP(j)
  const int lo = (i > WIN) ? (i - WIN) : 0;
  for(int j=MM+lo; j<=MM+i; j++) ATT_STEP(j)
#undef ATT_STEP

  const float inv = 1.f/l;
  const float* g = gate + hh*HD;
  float* yr = y + (size_t)(b*TT+i)*C + hh*HD;
#pragma unroll
  for(int d=0;d<HD;d++) yr[d] = acc[d]*inv*g[d];
}

// ---------------- router ----------------
__global__ void k_gate(const float* __restrict__ h2, const float* __restrict__ gw,
                       const float* __restrict__ gb, float* __restrict__ wout){
  int row = blockIdx.x*4 + (threadIdx.x>>6);
  int lane = threadIdx.x & 63;
  const float* hr = h2 + (size_t)row*C;
  float a0=0,a1=0,a2=0,a3=0;
  for(int c=lane;c<C;c+=64){
    float hv = hr[c];
    const float* g = gw + c*NE;
    a0+=hv*g[0]; a1+=hv*g[1]; a2+=hv*g[2]; a3+=hv*g[3];
  }
  a0=wsum(a0); a1=wsum(a1); a2=wsum(a2); a3=wsum(a3);
  if (lane==0){
    float p[4]={a0+gb[0],a1+gb[1],a2+gb[2],a3+gb[3]};
    float m = fmaxf(fmaxf(p[0],p[1]),fmaxf(p[2],p[3]));
    float s=0.f;
#pragma unroll
    for(int e=0;e<4;e++){ p[e]=expf(p[e]-m); s+=p[e]; }
#pragma unroll
    for(int e=0;e<4;e++) p[e] /= s;
    int i1=0;
    for(int e=1;e<4;e++) if(p[e]>p[i1]) i1=e;
    int i2=-1;
    for(int e=0;e<4;e++){ if(e==i1) continue; if(i2<0 || p[e]>p[i2]) i2=e; }
    float invs = 1.f/(p[i1]+p[i2]+1e-9f);
    float wv[4]={0.f,0.f,0.f,0.f};
    wv[i1]=p[i1]*invs; wv[i2]=p[i2]*invs;
    float* o = wout + (size_t)row*NE;
    o[0]=wv[0]; o[1]=wv[1]; o[2]=wv[2]; o[3]=wv[3];
  }
}

// ---------------- per-expert compaction + inverse map ----------------
__global__ __launch_bounds__(256) void k_compact(const float* __restrict__ wbuf,
    int* __restrict__ ridx, int* __restrict__ posmap, int* __restrict__ cnt){
  int e = blockIdx.x;
  int tid = threadIdx.x;
  int wave = tid>>6, lane = tid&63;
  __shared__ int wsum_s[4];
  __shared__ int base_s;
  if (tid==0) base_s = 0;
  __syncthreads();
  for(int t0=0; t0<NT; t0+=256){
    int t = t0 + tid;
    bool f = wbuf[(size_t)t*NE + e] > 0.f;
    unsigned long long bal = __ballot(f);
    int pre = __popcll(bal & ((1ull<<lane)-1ull));
    if (lane==0) wsum_s[wave] = __popcll(bal);
    __syncthreads();
    int off = 0;
#pragma unroll
    for(int w2=0;w2<4;w2++) if (w2 < wave) off += wsum_s[w2];
    int tot = wsum_s[0]+wsum_s[1]+wsum_s[2]+wsum_s[3];
    int b0 = base_s;
    int pos = b0 + off + pre;
    if (f) ridx[(size_t)e*NT + pos] = t;
    posmap[(size_t)t*NE + e] = f ? pos : -1;
    __syncthreads();
    if (tid==0) base_s = b0 + tot;
    __syncthreads();
  }
  if (tid==0) cnt[e] = base_s;
}

// ---------------- MoE gather: x[t] += sum_e w[t,e] * ye[ebase[e]+pos(t,e)] ----------------
__global__ __launch_bounds__(256) void k_moe_gather(const float* __restrict__ ye,
    const float* __restrict__ wbuf, const int* __restrict__ posmap,
    const int* __restrict__ cnt, float* __restrict__ x){
  int idx = blockIdx.x*256 + threadIdx.x;
  if (idx >= NT*(C/4)) return;
  int eb[NE]; int s=0;
#pragma unroll
  for(int e=0;e<NE;e++){ eb[e]=s; s+=cnt[e]; }
  int t = idx/(C/4), c4 = (idx - t*(C/4))*4;
  float4 acc = *(const float4*)(x + (size_t)t*C + c4);
#pragma unroll
  for(int e=0;e<NE;e++){
    int p = posmap[(size_t)t*NE + e];
    if (p >= 0){
      float w = wbuf[(size_t)t*NE + e];
      float4 yv = *(const float4*)(ye + (size_t)(eb[e]+p)*C + c4);
      acc.x += w*yv.x; acc.y += w*yv.y; acc.z += w*yv.z; acc.w += w*yv.w;
    }
  }
  *(float4*)(x + (size_t)t*C + c4) = acc;
}

extern "C" void kernel_launch(void* const* d_in, const int* in_sizes, int n_in,
                              void* d_out, int out_size, void* d_ws, size_t ws_size,
                              hipStream_t stream){
  (void)in_sizes; (void)n_in; (void)out_size; (void)ws_size;
  const int*   tokens  = (const int*)d_in[0];
  const float* tok_emb = (const float*)d_in[1];
  const float* pos_emb = (const float*)d_in[2];
  const float* mem     = (const float*)d_in[3];
  const float* ln1_w   = (const float*)d_in[4];
  const float* ln1_b   = (const float*)d_in[5];
  const float* qkv_w   = (const float*)d_in[6];
  const float* qkv_b   = (const float*)d_in[7];
  const float* proj_w  = (const float*)d_in[8];
  const float* proj_b  = (const float*)d_in[9];
  const float* attn_g  = (const float*)d_in[10];
  const float* th1_w   = (const float*)d_in[11];
  const float* th1_b   = (const float*)d_in[12];
  const float* th2_w   = (const float*)d_in[13];
  const float* th2_b   = (const float*)d_in[14];
  const float* ln2_w   = (const float*)d_in[15];
  const float* ln2_b   = (const float*)d_in[16];
  const float* gate_w  = (const float*)d_in[17];
  const float* gate_b  = (const float*)d_in[18];
  const float* e1_w    = (const float*)d_in[19];
  const float* e1_b    = (const float*)d_in[20];
  const float* e2_w    = (const float*)d_in[21];
  const float* e2_b    = (const float*)d_in[22];
  const float* lnf_w   = (const float*)d_in[23];
  const float* lnf_b   = (const float*)d_in[24];
  const float* head_w  = (const float*)d_in[25];
  const float* head_b  = (const float*)d_in[26];
  float* out = (float*)d_out;

  char* p = (char*)d_ws;
  float* x    = (float*)p; p += (size_t)NT*C*4;       // residual
  float* h    = (float*)p; p += (size_t)NT*C*4;       // LN out
  char*  rb   = p;                                     // shared region
  float* qkvb = (float*)rb;                            // qkv   [0, 75.5MB)
  float* sh   = (float*)(rb + (size_t)NT*N3C*4);       // y/t1  [75.5, 109MB)
  p += (size_t)NT*N3C*4 + (size_t)NT*TD*4*2;
  float* wbuf = (float*)p; p += (size_t)NT*NE*4;
  int*   ridx = (int*)p;   p += (size_t)NE*NT*4;
  int*   posm = (int*)p;   p += (size_t)NT*NE*4;
  int*   cnt  = (int*)p;   p += 64;
  float* he   = (float*)rb;                            // [0, 50.3MB)   (MoE phase)
  float* ye   = (float*)(rb + (size_t)2*NT*FCH*4);     // [50.3, 100.6) (MoE phase)

  dim3 b256(256);
  k_embed<<<dim3((NT*C+255)/256), b256, 0, stream>>>(tokens, tok_emb, pos_emb, x);
  for(int l=0;l<LAYERS;l++){
    k_ln<<<dim3(NT/4), b256, 0, stream>>>(x, ln1_w+l*C, ln1_b+l*C, h);
    k_gemm128<0,false,false,false><<<dim3(N3C/128, NT/128), b256, 0, stream>>>(
        h, qkv_w+(size_t)l*C*N3C, qkv_b+(size_t)l*N3C, nullptr, nullptr, 0, 0,
        qkvb, C, C, N3C, N3C);
    k_attn<<<dim3(BB*NH), b256, 0, stream>>>(qkvb, mem, attn_g+(size_t)l*C, sh);
    k_gemm64<0,true,false><<<dim3(C/128, NT/64), b256, 0, stream>>>(
        sh, proj_w+(size_t)l*C*C, proj_b+(size_t)l*C, nullptr, 0, 0,
        x, C, C, C, C);
    k_gemm64<1,false,false><<<dim3(TD/128, NT/64), b256, 0, stream>>>(
        x, th1_w+(size_t)l*C*TD, th1_b+(size_t)l*TD, nullptr, 0, 0,
        sh, C, C, TD, TD);
    k_gemm64<0,true,false><<<dim3(C/128, NT/64), b256, 0, stream>>>(
        sh, th2_w+(size_t)l*TD*C, th2_b+(size_t)l*C, nullptr, 0, 0,
        x, TD, TD, C, C);
    k_ln<<<dim3(NT/4), b256, 0, stream>>>(x, ln2_w+l*C, ln2_b+l*C, h);
    k_gate<<<dim3(NT/4), b256, 0, stream>>>(h, gate_w+(size_t)l*C*NE, gate_b+(size_t)l*NE, wbuf);
    k_compact<<<dim3(NE), b256, 0, stream>>>(wbuf, ridx, posm, cnt);
    for(int f0=0; f0<FF; f0+=FCH){
      k_gemm128<2,false,true,true><<<dim3(FCH/128, NT/128, NE), b256, 0, stream>>>(
          h, e1_w + (size_t)l*NE*C*FF + f0, e1_b + (size_t)l*NE*FF + f0,
          ridx, cnt, (size_t)C*FF, (size_t)FF,
          he, C, C, FF, FCH);
      if (f0==0)
        k_gemm64<0,false,true><<<dim3(C/128, NT/64, NE), b256, 0, stream>>>(
            he, e2_w + (size_t)l*NE*FF*C, e2_b + (size_t)l*NE*C,
            cnt, (size_t)FF*C, (size_t)C,
            ye, FCH, FCH, C, C);
      else
        k_gemm64<0,true,true><<<dim3(C/128, NT/64, NE), b256, 0, stream>>>(
            he, e2_w + (size_t)l*NE*FF*C + (size_t)f0*C, nullptr,
            cnt, (size_t)FF*C, (size_t)C,
            ye, FCH, FCH, C, C);
    }
    k_moe_gather<<<dim3((NT*(C/4)+255)/256), b256, 0, stream>>>(ye, wbuf, posm, cnt, x);
  }
  k_ln<<<dim3(NT/4), b256, 0, stream>>>(x, lnf_w, lnf_b, h);
  k_gemm64<0,false,false><<<dim3(NV/128, NT/64), b256, 0, stream>>>(
      h, head_w, head_b, nullptr, 0, 0,
      out, C, C, NV, NV);
}

// Round 9
// 39303.027 us; speedup vs baseline: 5.6384x; 5.6384x over previous
//
#include <hip/hip_runtime.h>
#include <math.h>

#define LAYERS 8
#define C 384
#define NH 8
#define NE 4
#define TD 256
#define NV 256
#define WIN 64
#define MM 56
#define HD 48
#define BB 64
#define TT 256
#define NT (BB*TT)
#define N3C 1152
#define FF 1536
#define KV 312
#define FCH 384              // MoE FF chunk width
#define SCALE_QK 0.14433756729740643f

static __device__ __forceinline__ float wsum(float v){
#pragma unroll
  for(int o=32;o;o>>=1) v += __shfl_xor(v,o);
  return v;
}

// ---------------- embed ----------------
__global__ void k_embed(const int* __restrict__ tokens, const float* __restrict__ tok_emb,
                        const float* __restrict__ pos_emb, float* __restrict__ x){
  int idx = blockIdx.x*256 + threadIdx.x;
  if (idx >= NT*C) return;
  int t = idx / C, c = idx - t*C;
  x[idx] = tok_emb[tokens[t]*C + c] + pos_emb[(t % TT)*C + c];
}

// ---------------- layernorm (wave per row) ----------------
__global__ void k_ln(const float* __restrict__ in, const float* __restrict__ w,
                     const float* __restrict__ b, float* __restrict__ out){
  int row = blockIdx.x*4 + (threadIdx.x>>6);
  int lane = threadIdx.x & 63;
  const float* xr = in + (size_t)row*C;
  float v[6]; float s = 0.f;
#pragma unroll
  for(int i=0;i<6;i++){ v[i]=xr[lane+64*i]; s+=v[i]; }
  s = wsum(s);
  float mu = s*(1.f/C);
  float q=0.f;
#pragma unroll
  for(int i=0;i<6;i++){ float d=v[i]-mu; q+=d*d; }
  q = wsum(q);
  float inv = rsqrtf(q*(1.f/C)+1e-5f);
  float* orow = out + (size_t)row*C;
#pragma unroll
  for(int i=0;i<6;i++){ int c=lane+64*i; orow[c] = (v[i]-mu)*inv*w[c]+b[c]; }
}

// ---------------- GEMM 128x128, BK=32, single LDS buffer, 8x8/thread ----------------
// Schedule per tile: barrier -> issue next-tile globals -> 32kk compute -> barrier -> ds_write.
// NOTE: no min-waves in launch_bounds — a VGPR cap below acc(64)+staging(32) spills
// acc to scratch (round-8 lesson: 12 GB scratch traffic/dispatch, 15x regression).
// ACT: 0 none, 1 tanh, 2 gelu. MOE: z=expert; GATHER: A rows via ridx.
template<int ACT, bool ACCUM, bool MOE, bool GATHER>
__global__ __launch_bounds__(256) void k_gemm128(
    const float* __restrict__ A, const float* __restrict__ W,
    const float* __restrict__ bias,
    const int* __restrict__ ridx, const int* __restrict__ cnt,
    size_t sWz, size_t sBz,
    float* __restrict__ Cout, int Kn, int ldA, int ldB, int ldC)
{
  const int z = MOE ? (int)blockIdx.z : 0;
  int Mn = NT;
  if (MOE){
    int eb = 0;
#pragma unroll
    for(int i=0;i<NE;i++){ int ci = cnt[i]; if (i<z) eb += ci; if (i==z) Mn = ci; }
    W += (size_t)z*sWz;
    if (bias) bias += (size_t)z*sBz;
    if (!GATHER) A += (size_t)eb*ldA;
    Cout += (size_t)eb*ldC;
  }
  const int bm = (int)blockIdx.y<<7, bn = (int)blockIdx.x<<7;
  if (bm >= Mn) return;
  __shared__ __attribute__((aligned(16))) float As[32][132];
  __shared__ __attribute__((aligned(16))) float Bs[32][132];
  const int tid = threadIdx.x;
  const int tx = tid&15, ty = tid>>4;
  const int arow = tid>>1, ak = (tid&1)<<4;   // A: 2 thr/row, 16-k half each
  const int brow = tid>>3, bc = (tid&7)<<4;   // B: 8 thr/row, 16 cols each
  int r0 = bm + arow; if (r0 >= Mn) r0 = Mn-1;
  const int agr = GATHER ? ridx[(size_t)z*NT + r0] : r0;
  const float* Arow = A + (size_t)agr*ldA + ak;
  const float* Wrow = W + (size_t)brow*ldB + bn + bc;
  float4 a0 = *(const float4*)(Arow);
  float4 a1 = *(const float4*)(Arow+4);
  float4 a2 = *(const float4*)(Arow+8);
  float4 a3 = *(const float4*)(Arow+12);
  float4 b0 = *(const float4*)(Wrow);
  float4 b1 = *(const float4*)(Wrow+4);
  float4 b2 = *(const float4*)(Wrow+8);
  float4 b3 = *(const float4*)(Wrow+12);
  // stage tile 0
  {
    As[ak+ 0][arow]=a0.x; As[ak+ 1][arow]=a0.y; As[ak+ 2][arow]=a0.z; As[ak+ 3][arow]=a0.w;
    As[ak+ 4][arow]=a1.x; As[ak+ 5][arow]=a1.y; As[ak+ 6][arow]=a1.z; As[ak+ 7][arow]=a1.w;
    As[ak+ 8][arow]=a2.x; As[ak+ 9][arow]=a2.y; As[ak+10][arow]=a2.z; As[ak+11][arow]=a2.w;
    As[ak+12][arow]=a3.x; As[ak+13][arow]=a3.y; As[ak+14][arow]=a3.z; As[ak+15][arow]=a3.w;
    *(float4*)&Bs[brow][bc]    = b0;
    *(float4*)&Bs[brow][bc+4]  = b1;
    *(float4*)&Bs[brow][bc+8]  = b2;
    *(float4*)&Bs[brow][bc+12] = b3;
  }
  float acc[8][8] = {};
  const int T = Kn>>5;
  for (int t=0; t<T; t++){
    __syncthreads();                      // staged tile visible
    const bool more = (t+1 < T);
    if (more){
      const int k1 = (t+1)<<5;
      a0 = *(const float4*)(Arow + k1);
      a1 = *(const float4*)(Arow + k1 + 4);
      a2 = *(const float4*)(Arow + k1 + 8);
      a3 = *(const float4*)(Arow + k1 + 12);
      const float* wr = Wrow + (size_t)k1*ldB;
      b0 = *(const float4*)(wr);
      b1 = *(const float4*)(wr+4);
      b2 = *(const float4*)(wr+8);
      b3 = *(const float4*)(wr+12);
    }
#pragma unroll
    for (int kk=0;kk<32;kk++){
      float av[8], bv[8];
      *(float4*)&av[0] = *(const float4*)&As[kk][ty<<3];
      *(float4*)&av[4] = *(const float4*)&As[kk][(ty<<3)+4];
      *(float4*)&bv[0] = *(const float4*)&Bs[kk][tx<<2];
      *(float4*)&bv[4] = *(const float4*)&Bs[kk][64+(tx<<2)];
#pragma unroll
      for(int i=0;i<8;i++)
#pragma unroll
        for(int j=0;j<8;j++) acc[i][j] += av[i]*bv[j];
    }
    __syncthreads();                      // compute done
    if (more){
      As[ak+ 0][arow]=a0.x; As[ak+ 1][arow]=a0.y; As[ak+ 2][arow]=a0.z; As[ak+ 3][arow]=a0.w;
      As[ak+ 4][arow]=a1.x; As[ak+ 5][arow]=a1.y; As[ak+ 6][arow]=a1.z; As[ak+ 7][arow]=a1.w;
      As[ak+ 8][arow]=a2.x; As[ak+ 9][arow]=a2.y; As[ak+10][arow]=a2.z; As[ak+11][arow]=a2.w;
      As[ak+12][arow]=a3.x; As[ak+13][arow]=a3.y; As[ak+14][arow]=a3.z; As[ak+15][arow]=a3.w;
      *(float4*)&Bs[brow][bc]    = b0;
      *(float4*)&Bs[brow][bc+4]  = b1;
      *(float4*)&Bs[brow][bc+8]  = b2;
      *(float4*)&Bs[brow][bc+12] = b3;
    }
  }
  const int c0 = bn + (tx<<2), c1 = c0 + 64;
  float4 bias0 = make_float4(0,0,0,0), bias1 = make_float4(0,0,0,0);
  if (bias){ bias0 = *(const float4*)&bias[c0]; bias1 = *(const float4*)&bias[c1]; }
#pragma unroll
  for(int i=0;i<8;i++){
    const int row = bm + (ty<<3) + i;
    if (row < Mn){
      float v[8];
      v[0]=acc[i][0]+bias0.x; v[1]=acc[i][1]+bias0.y; v[2]=acc[i][2]+bias0.z; v[3]=acc[i][3]+bias0.w;
      v[4]=acc[i][4]+bias1.x; v[5]=acc[i][5]+bias1.y; v[6]=acc[i][6]+bias1.z; v[7]=acc[i][7]+bias1.w;
#pragma unroll
      for(int j=0;j<8;j++){
        if (ACT==1) v[j] = tanhf(v[j]);
        if (ACT==2) v[j] = 0.5f*v[j]*(1.0f+erff(v[j]*0.70710678118654752f));
      }
      float* p0 = Cout + (size_t)row*ldC + c0;
      float* p1 = Cout + (size_t)row*ldC + c1;
      float4 w0 = make_float4(v[0],v[1],v[2],v[3]);
      float4 w1 = make_float4(v[4],v[5],v[6],v[7]);
      if (ACCUM){
        float4 o0 = *(const float4*)p0, o1 = *(const float4*)p1;
        w0.x+=o0.x; w0.y+=o0.y; w0.z+=o0.z; w0.w+=o0.w;
        w1.x+=o1.x; w1.y+=o1.y; w1.z+=o1.z; w1.w+=o1.w;
      }
      *(float4*)p0 = w0;
      *(float4*)p1 = w1;
    }
  }
}

// ---------------- GEMM 64x128, BK=32, single LDS buffer, 4x8/thread ----------------
// For small-N GEMMs: doubles the grid (M/64 blocks) for CU co-residency.
template<int ACT, bool ACCUM, bool MOE>
__global__ __launch_bounds__(256) void k_gemm64(
    const float* __restrict__ A, const float* __restrict__ W,
    const float* __restrict__ bias,
    const int* __restrict__ cnt,
    size_t sWz, size_t sBz,
    float* __restrict__ Cout, int Kn, int ldA, int ldB, int ldC)
{
  const int z = MOE ? (int)blockIdx.z : 0;
  int Mn = NT;
  if (MOE){
    int eb = 0;
#pragma unroll
    for(int i=0;i<NE;i++){ int ci = cnt[i]; if (i<z) eb += ci; if (i==z) Mn = ci; }
    W += (size_t)z*sWz;
    if (bias) bias += (size_t)z*sBz;
    A += (size_t)eb*ldA;
    Cout += (size_t)eb*ldC;
  }
  const int bm = (int)blockIdx.y<<6, bn = (int)blockIdx.x<<7;
  if (bm >= Mn) return;
  __shared__ __attribute__((aligned(16))) float As[32][68];
  __shared__ __attribute__((aligned(16))) float Bs[32][132];
  const int tid = threadIdx.x;
  const int tx = tid&15, ty = tid>>4;
  const int arow = tid>>2, ak = (tid&3)<<3;   // A: 4 thr/row, 8-k each
  const int brow = tid>>3, bc = (tid&7)<<4;   // B: 8 thr/row, 16 cols each
  int r0 = bm + arow; if (r0 >= Mn) r0 = Mn-1;
  const float* Arow = A + (size_t)r0*ldA + ak;
  const float* Wrow = W + (size_t)brow*ldB + bn + bc;
  float4 a0 = *(const float4*)(Arow);
  float4 a1 = *(const float4*)(Arow+4);
  float4 b0 = *(const float4*)(Wrow);
  float4 b1 = *(const float4*)(Wrow+4);
  float4 b2 = *(const float4*)(Wrow+8);
  float4 b3 = *(const float4*)(Wrow+12);
  {
    As[ak+0][arow]=a0.x; As[ak+1][arow]=a0.y; As[ak+2][arow]=a0.z; As[ak+3][arow]=a0.w;
    As[ak+4][arow]=a1.x; As[ak+5][arow]=a1.y; As[ak+6][arow]=a1.z; As[ak+7][arow]=a1.w;
    *(float4*)&Bs[brow][bc]    = b0;
    *(float4*)&Bs[brow][bc+4]  = b1;
    *(float4*)&Bs[brow][bc+8]  = b2;
    *(float4*)&Bs[brow][bc+12] = b3;
  }
  float acc[4][8] = {};
  const int T = Kn>>5;
  for (int t=0; t<T; t++){
    __syncthreads();
    const bool more = (t+1 < T);
    if (more){
      const int k1 = (t+1)<<5;
      a0 = *(const float4*)(Arow + k1);
      a1 = *(const float4*)(Arow + k1 + 4);
      const float* wr = Wrow + (size_t)k1*ldB;
      b0 = *(const float4*)(wr);
      b1 = *(const float4*)(wr+4);
      b2 = *(const float4*)(wr+8);
      b3 = *(const float4*)(wr+12);
    }
#pragma unroll
    for (int kk=0;kk<32;kk++){
      float av[4], bv[8];
      *(float4*)&av[0] = *(const float4*)&As[kk][ty<<2];
      *(float4*)&bv[0] = *(const float4*)&Bs[kk][tx<<2];
      *(float4*)&bv[4] = *(const float4*)&Bs[kk][64+(tx<<2)];
#pragma unroll
      for(int i=0;i<4;i++)
#pragma unroll
        for(int j=0;j<8;j++) acc[i][j] += av[i]*bv[j];
    }
    __syncthreads();
    if (more){
      As[ak+0][arow]=a0.x; As[ak+1][arow]=a0.y; As[ak+2][arow]=a0.z; As[ak+3][arow]=a0.w;
      As[ak+4][arow]=a1.x; As[ak+5][arow]=a1.y; As[ak+6][arow]=a1.z; As[ak+7][arow]=a1.w;
      *(float4*)&Bs[brow][bc]    = b0;
      *(float4*)&Bs[brow][bc+4]  = b1;
      *(float4*)&Bs[brow][bc+8]  = b2;
      *(float4*)&Bs[brow][bc+12] = b3;
    }
  }
  const int c0 = bn + (tx<<2), c1 = c0 + 64;
  float4 bias0 = make_float4(0,0,0,0), bias1 = make_float4(0,0,0,0);
  if (bias){ bias0 = *(const float4*)&bias[c0]; bias1 = *(const float4*)&bias[c1]; }
#pragma unroll
  for(int i=0;i<4;i++){
    const int row = bm + (ty<<2) + i;
    if (row < Mn){
      float v[8];
      v[0]=acc[i][0]+bias0.x; v[1]=acc[i][1]+bias0.y; v[2]=acc[i][2]+bias0.z; v[3]=acc[i][3]+bias0.w;
      v[4]=acc[i][4]+bias1.x; v[5]=acc[i][5]+bias1.y; v[6]=acc[i][6]+bias1.z; v[7]=acc[i][7]+bias1.w;
#pragma unroll
      for(int j=0;j<8;j++){
        if (ACT==1) v[j] = tanhf(v[j]);
        if (ACT==2) v[j] = 0.5f*v[j]*(1.0f+erff(v[j]*0.70710678118654752f));
      }
      float* p0 = Cout + (size_t)row*ldC + c0;
      float* p1 = Cout + (size_t)row*ldC + c1;
      float4 w0 = make_float4(v[0],v[1],v[2],v[3]);
      float4 w1 = make_float4(v[4],v[5],v[6],v[7]);
      if (ACCUM){
        float4 o0 = *(const float4*)p0, o1 = *(const float4*)p1;
        w0.x+=o0.x; w0.y+=o0.y; w0.z+=o0.z; w0.w+=o0.w;
        w1.x+=o1.x; w1.y+=o1.y; w1.z+=o1.z; w1.w+=o1.w;
      }
      *(float4*)p0 = w0;
      *(float4*)p1 = w1;
    }
  }
}

// ---------------- attention: block per (b,head); lane-per-query 1-pass flash ----------------
__global__ __launch_bounds__(256) void k_attn(const float* __restrict__ qkv,
    const float* __restrict__ mem, const float* __restrict__ gate,
    float* __restrict__ y){
  __shared__ float ks[KV*50];
  __shared__ float vs[KV*50];
  const int b = blockIdx.x >> 3, hh = blockIdx.x & 7;
  const int tid = threadIdx.x;
  for(int idx=tid; idx<KV*24; idx+=256){
    int j = idx/24, f = (idx - j*24)*2;
    float2 kvv, vvv;
    if (j < MM){
      kvv = *(const float2*)(mem + j*C + hh*HD + f);
      vvv = kvv;
    } else {
      const float* row = qkv + (size_t)(b*TT + j - MM)*N3C + hh*HD + f;
      kvv = *(const float2*)(row + C);
      vvv = *(const float2*)(row + 2*C);
    }
    *(float2*)(ks + j*50 + f) = kvv;
    *(float2*)(vs + j*50 + f) = vvv;
  }
  __syncthreads();
  const int i = tid;
  const float* qrow = qkv + (size_t)(b*TT+i)*N3C + hh*HD;
  float q[HD];
#pragma unroll
  for(int d2=0; d2<24; d2++){
    float2 qv = *(const float2*)(qrow + d2*2);
    q[d2*2] = qv.x; q[d2*2+1] = qv.y;
  }
  float m = -1e30f, l = 0.f;
  float acc[HD];
#pragma unroll
  for(int d=0;d<HD;d++) acc[d]=0.f;

#define ATT_STEP(JROW) {                                            \
    const float* kr = ks + (JROW)*50;                               \
    float dot = 0.f;                                                \
    _Pragma("unroll")                                               \
    for(int d2=0; d2<24; d2++){                                     \
      float2 kv2 = *(const float2*)(kr + d2*2);                     \
      dot += q[d2*2]*kv2.x + q[d2*2+1]*kv2.y;                       \
    }                                                               \
    float s = dot*SCALE_QK;                                         \
    if (s > m + 8.f){                                               \
      float f_ = __expf(m - s);                                     \
      l *= f_;                                                      \
      _Pragma("unroll")                                             \
      for(int d=0; d<HD; d++) acc[d] *= f_;                         \
      m = s;                                                        \
    }                                                               \
    float pch = __expf(s - m);                                      \
    l += pch;                                                       \
    const float* vr = vs + (JROW)*50;                               \
    _Pragma("unroll")                                               \
    for(int d2=0; d2<24; d2++){                                     \
      float2 vv2 = *(const float2*)(vr + d2*2);                     \
      acc[d2*2]   += pch*vv2.x;                                     \
      acc[d2*2+1] += pch*vv2.y;                                     \
    }                                                               \
  }

  for(int j=0; j<MM; j++) ATT_STEP(j)
  const int lo = (i > WIN) ? (i - WIN) : 0;
  for(int j=MM+lo; j<=MM+i; j++) ATT_STEP(j)
#undef ATT_STEP

  const float inv = 1.f/l;
  const float* g = gate + hh*HD;
  float* yr = y + (size_t)(b*TT+i)*C + hh*HD;
#pragma unroll
  for(int d=0;d<HD;d++) yr[d] = acc[d]*inv*g[d];
}

// ---------------- router ----------------
__global__ void k_gate(const float* __restrict__ h2, const float* __restrict__ gw,
                       const float* __restrict__ gb, float* __restrict__ wout){
  int row = blockIdx.x*4 + (threadIdx.x>>6);
  int lane = threadIdx.x & 63;
  const float* hr = h2 + (size_t)row*C;
  float a0=0,a1=0,a2=0,a3=0;
  for(int c=lane;c<C;c+=64){
    float hv = hr[c];
    const float* g = gw + c*NE;
    a0+=hv*g[0]; a1+=hv*g[1]; a2+=hv*g[2]; a3+=hv*g[3];
  }
  a0=wsum(a0); a1=wsum(a1); a2=wsum(a2); a3=wsum(a3);
  if (lane==0){
    float p[4]={a0+gb[0],a1+gb[1],a2+gb[2],a3+gb[3]};
    float m = fmaxf(fmaxf(p[0],p[1]),fmaxf(p[2],p[3]));
    float s=0.f;
#pragma unroll
    for(int e=0;e<4;e++){ p[e]=expf(p[e]-m); s+=p[e]; }
#pragma unroll
    for(int e=0;e<4;e++) p[e] /= s;
    int i1=0;
    for(int e=1;e<4;e++) if(p[e]>p[i1]) i1=e;
    int i2=-1;
    for(int e=0;e<4;e++){ if(e==i1) continue; if(i2<0 || p[e]>p[i2]) i2=e; }
    float invs = 1.f/(p[i1]+p[i2]+1e-9f);
    float wv[4]={0.f,0.f,0.f,0.f};
    wv[i1]=p[i1]*invs; wv[i2]=p[i2]*invs;
    float* o = wout + (size_t)row*NE;
    o[0]=wv[0]; o[1]=wv[1]; o[2]=wv[2]; o[3]=wv[3];
  }
}

// ---------------- per-expert compaction + inverse map ----------------
__global__ __launch_bounds__(256) void k_compact(const float* __restrict__ wbuf,
    int* __restrict__ ridx, int* __restrict__ posmap, int* __restrict__ cnt){
  int e = blockIdx.x;
  int tid = threadIdx.x;
  int wave = tid>>6, lane = tid&63;
  __shared__ int wsum_s[4];
  __shared__ int base_s;
  if (tid==0) base_s = 0;
  __syncthreads();
  for(int t0=0; t0<NT; t0+=256){
    int t = t0 + tid;
    bool f = wbuf[(size_t)t*NE + e] > 0.f;
    unsigned long long bal = __ballot(f);
    int pre = __popcll(bal & ((1ull<<lane)-1ull));
    if (lane==0) wsum_s[wave] = __popcll(bal);
    __syncthreads();
    int off = 0;
#pragma unroll
    for(int w2=0;w2<4;w2++) if (w2 < wave) off += wsum_s[w2];
    int tot = wsum_s[0]+wsum_s[1]+wsum_s[2]+wsum_s[3];
    int b0 = base_s;
    int pos = b0 + off + pre;
    if (f) ridx[(size_t)e*NT + pos] = t;
    posmap[(size_t)t*NE + e] = f ? pos : -1;
    __syncthreads();
    if (tid==0) base_s = b0 + tot;
    __syncthreads();
  }
  if (tid==0) cnt[e] = base_s;
}

// ---------------- MoE gather: x[t] += sum_e w[t,e] * ye[ebase[e]+pos(t,e)] ----------------
__global__ __launch_bounds__(256) void k_moe_gather(const float* __restrict__ ye,
    const float* __restrict__ wbuf, const int* __restrict__ posmap,
    const int* __restrict__ cnt, float* __restrict__ x){
  int idx = blockIdx.x*256 + threadIdx.x;
  if (idx >= NT*(C/4)) return;
  int eb[NE]; int s=0;
#pragma unroll
  for(int e=0;e<NE;e++){ eb[e]=s; s+=cnt[e]; }
  int t = idx/(C/4), c4 = (idx - t*(C/4))*4;
  float4 acc = *(const float4*)(x + (size_t)t*C + c4);
#pragma unroll
  for(int e=0;e<NE;e++){
    int p = posmap[(size_t)t*NE + e];
    if (p >= 0){
      float w = wbuf[(size_t)t*NE + e];
      float4 yv = *(const float4*)(ye + (size_t)(eb[e]+p)*C + c4);
      acc.x += w*yv.x; acc.y += w*yv.y; acc.z += w*yv.z; acc.w += w*yv.w;
    }
  }
  *(float4*)(x + (size_t)t*C + c4) = acc;
}

extern "C" void kernel_launch(void* const* d_in, const int* in_sizes, int n_in,
                              void* d_out, int out_size, void* d_ws, size_t ws_size,
                              hipStream_t stream){
  (void)in_sizes; (void)n_in; (void)out_size; (void)ws_size;
  const int*   tokens  = (const int*)d_in[0];
  const float* tok_emb = (const float*)d_in[1];
  const float* pos_emb = (const float*)d_in[2];
  const float* mem     = (const float*)d_in[3];
  const float* ln1_w   = (const float*)d_in[4];
  const float* ln1_b   = (const float*)d_in[5];
  const float* qkv_w   = (const float*)d_in[6];
  const float* qkv_b   = (const float*)d_in[7];
  const float* proj_w  = (const float*)d_in[8];
  const float* proj_b  = (const float*)d_in[9];
  const float* attn_g  = (const float*)d_in[10];
  const float* th1_w   = (const float*)d_in[11];
  const float* th1_b   = (const float*)d_in[12];
  const float* th2_w   = (const float*)d_in[13];
  const float* th2_b   = (const float*)d_in[14];
  const float* ln2_w   = (const float*)d_in[15];
  const float* ln2_b   = (const float*)d_in[16];
  const float* gate_w  = (const float*)d_in[17];
  const float* gate_b  = (const float*)d_in[18];
  const float* e1_w    = (const float*)d_in[19];
  const float* e1_b    = (const float*)d_in[20];
  const float* e2_w    = (const float*)d_in[21];
  const float* e2_b    = (const float*)d_in[22];
  const float* lnf_w   = (const float*)d_in[23];
  const float* lnf_b   = (const float*)d_in[24];
  const float* head_w  = (const float*)d_in[25];
  const float* head_b  = (const float*)d_in[26];
  float* out = (float*)d_out;

  char* p = (char*)d_ws;
  float* x    = (float*)p; p += (size_t)NT*C*4;       // residual
  float* h    = (float*)p; p += (size_t)NT*C*4;       // LN out
  char*  rb   = p;                                     // shared region
  float* qkvb = (float*)rb;                            // qkv   [0, 75.5MB)
  float* sh   = (float*)(rb + (size_t)NT*N3C*4);       // y/t1  [75.5, 109MB)
  p += (size_t)NT*N3C*4 + (size_t)NT*TD*4*2;
  float* wbuf = (float*)p; p += (size_t)NT*NE*4;
  int*   ridx = (int*)p;   p += (size_t)NE*NT*4;
  int*   posm = (int*)p;   p += (size_t)NT*NE*4;
  int*   cnt  = (int*)p;   p += 64;
  float* he   = (float*)rb;                            // [0, 50.3MB)   (MoE phase)
  float* ye   = (float*)(rb + (size_t)2*NT*FCH*4);     // [50.3, 100.6) (MoE phase)

  dim3 b256(256);
  k_embed<<<dim3((NT*C+255)/256), b256, 0, stream>>>(tokens, tok_emb, pos_emb, x);
  for(int l=0;l<LAYERS;l++){
    k_ln<<<dim3(NT/4), b256, 0, stream>>>(x, ln1_w+l*C, ln1_b+l*C, h);
    k_gemm128<0,false,false,false><<<dim3(N3C/128, NT/128), b256, 0, stream>>>(
        h, qkv_w+(size_t)l*C*N3C, qkv_b+(size_t)l*N3C, nullptr, nullptr, 0, 0,
        qkvb, C, C, N3C, N3C);
    k_attn<<<dim3(BB*NH), b256, 0, stream>>>(qkvb, mem, attn_g+(size_t)l*C, sh);
    k_gemm64<0,true,false><<<dim3(C/128, NT/64), b256, 0, stream>>>(
        sh, proj_w+(size_t)l*C*C, proj_b+(size_t)l*C, nullptr, 0, 0,
        x, C, C, C, C);
    k_gemm64<1,false,false><<<dim3(TD/128, NT/64), b256, 0, stream>>>(
        x, th1_w+(size_t)l*C*TD, th1_b+(size_t)l*TD, nullptr, 0, 0,
        sh, C, C, TD, TD);
    k_gemm64<0,true,false><<<dim3(C/128, NT/64), b256, 0, stream>>>(
        sh, th2_w+(size_t)l*TD*C, th2_b+(size_t)l*C, nullptr, 0, 0,
        x, TD, TD, C, C);
    k_ln<<<dim3(NT/4), b256, 0, stream>>>(x, ln2_w+l*C, ln2_b+l*C, h);
    k_gate<<<dim3(NT/4), b256, 0, stream>>>(h, gate_w+(size_t)l*C*NE, gate_b+(size_t)l*NE, wbuf);
    k_compact<<<dim3(NE), b256, 0, stream>>>(wbuf, ridx, posm, cnt);
    for(int f0=0; f0<FF; f0+=FCH){
      k_gemm128<2,false,true,true><<<dim3(FCH/128, NT/128, NE), b256, 0, stream>>>(
          h, e1_w + (size_t)l*NE*C*FF + f0, e1_b + (size_t)l*NE*FF + f0,
          ridx, cnt, (size_t)C*FF, (size_t)FF,
          he, C, C, FF, FCH);
      if (f0==0)
        k_gemm64<0,false,true><<<dim3(C/128, NT/64, NE), b256, 0, stream>>>(
            he, e2_w + (size_t)l*NE*FF*C, e2_b + (size_t)l*NE*C,
            cnt, (size_t)FF*C, (size_t)C,
            ye, FCH, FCH, C, C);
      else
        k_gemm64<0,true,true><<<dim3(C/128, NT/64, NE), b256, 0, stream>>>(
            he, e2_w + (size_t)l*NE*FF*C + (size_t)f0*C, nullptr,
            cnt, (size_t)FF*C, (size_t)C,
            ye, FCH, FCH, C, C);
    }
    k_moe_gather<<<dim3((NT*(C/4)+255)/256), b256, 0, stream>>>(ye, wbuf, posm, cnt, x);
  }
  k_ln<<<dim3(NT/4), b256, 0, stream>>>(x, lnf_w, lnf_b, h);
  k_gemm64<0,false,false><<<dim3(NV/128, NT/64), b256, 0, stream>>>(
      h, head_w, head_b, nullptr, 0, 0,
      out, C, C, NV, NV);
}

// Round 10
// 22326.175 us; speedup vs baseline: 9.9258x; 1.7604x over previous
//
#include <hip/hip_runtime.h>
#include <math.h>

#define LAYERS 8
#define C 384
#define NH 8
#define NE 4
#define TD 256
#define NV 256
#define WIN 64
#define MM 56
#define HD 48
#define BB 64
#define TT 256
#define NT (BB*TT)
#define N3C 1152
#define FF 1536
#define KV 312
#define FCH 384
#define SCALE_QK 0.14433756729740643f

static __device__ __forceinline__ float wsum(float v){
#pragma unroll
  for(int o=32;o;o>>=1) v += __shfl_xor(v,o);
  return v;
}

#define GLOAD16(g,l) __builtin_amdgcn_global_load_lds( \
  (const __attribute__((address_space(1))) void*)(g), \
  (__attribute__((address_space(3))) void*)(l), 16, 0, 0)

// ---------------- embed ----------------
__global__ void k_embed(const int* __restrict__ tokens, const float* __restrict__ tok_emb,
                        const float* __restrict__ pos_emb, float* __restrict__ x){
  int idx = blockIdx.x*256 + threadIdx.x;
  if (idx >= NT*C) return;
  int t = idx / C, c = idx - t*C;
  x[idx] = tok_emb[tokens[t]*C + c] + pos_emb[(t % TT)*C + c];
}

// ---------------- layernorm (wave per row) ----------------
__global__ void k_ln(const float* __restrict__ in, const float* __restrict__ w,
                     const float* __restrict__ b, float* __restrict__ out){
  int row = blockIdx.x*4 + (threadIdx.x>>6);
  int lane = threadIdx.x & 63;
  const float* xr = in + (size_t)row*C;
  float v[6]; float s = 0.f;
#pragma unroll
  for(int i=0;i<6;i++){ v[i]=xr[lane+64*i]; s+=v[i]; }
  s = wsum(s);
  float mu = s*(1.f/C);
  float q=0.f;
#pragma unroll
  for(int i=0;i<6;i++){ float d=v[i]-mu; q+=d*d; }
  q = wsum(q);
  float inv = rsqrtf(q*(1.f/C)+1e-5f);
  float* orow = out + (size_t)row*C;
#pragma unroll
  for(int i=0;i<6;i++){ int c=lane+64*i; orow[c] = (v[i]-mu)*inv*w[c]+b[c]; }
}

// ---------------- fp32 GEMM: 128xTN tile, BK=16, 256 thr ----------------
// A: register-staged (8 regs) into transposed As[16][132] (conflict-free frag reads).
// B: staged HBM->LDS via global_load_lds (zero staging VGPRs, no ds_write),
//    double-buffered Bs[2][16][TN] so each DMA has a full compute phase in
//    flight before any barrier's vmcnt(0) drain (round-7/9 lesson: never hold
//    >16 staged floats in regs across the unrolled compute loop).
// ACT: 0 none, 1 tanh, 2 gelu. MOE: z=expert; GATHER: A rows via ridx.
template<int ACT, bool ACCUM, bool MOE, bool GATHER, int TN>
__global__ __launch_bounds__(256) void k_gemm(
    const float* __restrict__ A, const float* __restrict__ W,
    const float* __restrict__ bias,
    const int* __restrict__ ridx, const int* __restrict__ cnt,
    size_t sWz, size_t sBz,
    float* __restrict__ Cout, int Kn, int ldA, int ldB, int ldC)
{
  const int z = MOE ? (int)blockIdx.z : 0;
  int Mn = NT;
  if (MOE){
    int eb = 0;
#pragma unroll
    for(int i=0;i<NE;i++){ int ci = cnt[i]; if (i<z) eb += ci; if (i==z) Mn = ci; }
    W += (size_t)z*sWz;
    if (bias) bias += (size_t)z*sBz;
    if (!GATHER) A += (size_t)eb*ldA;
    Cout += (size_t)eb*ldC;
  }
  const int bm = (int)blockIdx.y<<7, bn = (int)blockIdx.x*TN;
  if (bm >= Mn) return;
  __shared__ __attribute__((aligned(16))) float As[16][132];
  __shared__ __attribute__((aligned(16))) float Bs[2][16][TN];
  const int tid = threadIdx.x;
  const int tx = tid&15, ty = tid>>4;
  const int wave = tid>>6, lane = tid&63;
  // A staging: 2 thr/row, 8-k half each
  const int arow = tid>>1, ah = tid&1;
  int r0 = bm + arow; if (r0 >= Mn) r0 = Mn-1;
  const int agr = GATHER ? ridx[(size_t)z*NT + r0] : r0;
  const float* Arow = A + (size_t)agr*ldA + (ah<<3);
  // B gload source: per-lane global addr, wave-linear LDS dest
  const float* gB0;
  if (TN==128) gB0 = W + (size_t)(4*wave + (lane>>5))*ldB + bn + ((lane&31)<<2);
  else         gB0 = W + (size_t)(4*wave + (lane>>4))*ldB + bn + ((lane&15)<<2);

#define STAGE_B(buf, k0) {                                                      \
    if (TN==128){                                                               \
      GLOAD16(gB0 + (size_t)(k0)*ldB,                                           \
              (char*)&Bs[0][0][0] + (size_t)(buf)*8192 + wave*2048);            \
      GLOAD16(gB0 + (size_t)((k0)+2)*ldB,                                       \
              (char*)&Bs[0][0][0] + (size_t)(buf)*8192 + wave*2048 + 1024);     \
    } else {                                                                    \
      GLOAD16(gB0 + (size_t)(k0)*ldB,                                           \
              (char*)&Bs[0][0][0] + (size_t)(buf)*4096 + wave*1024);            \
    }                                                                           \
  }

  // prologue: tile 0
  float4 a0 = *(const float4*)(Arow);
  float4 a1 = *(const float4*)(Arow+4);
  STAGE_B(0, 0);
  {
    const int kk0 = ah<<3;
    As[kk0+0][arow]=a0.x; As[kk0+1][arow]=a0.y; As[kk0+2][arow]=a0.z; As[kk0+3][arow]=a0.w;
    As[kk0+4][arow]=a1.x; As[kk0+5][arow]=a1.y; As[kk0+6][arow]=a1.z; As[kk0+7][arow]=a1.w;
  }
  constexpr int NJ = TN/16;
  float acc[8][NJ] = {};
  const int T = Kn>>4;
  for (int t=0; t<T; t++){
    __syncthreads();                      // publishes As writes; drains B[t] DMA
    const bool more = (t+1 < T);
    if (more){
      STAGE_B((t+1)&1, (t+1)<<4);        // DMA B[t+1] into other buffer (hidden under compute)
      a0 = *(const float4*)(Arow + ((t+1)<<4));
      a1 = *(const float4*)(Arow + ((t+1)<<4) + 4);
    }
    const float* Bc = &Bs[t&1][0][0];
#pragma unroll
    for (int kk=0;kk<16;kk++){
      float av[8], bv[NJ];
      *(float4*)&av[0] = *(const float4*)&As[kk][ty<<3];
      *(float4*)&av[4] = *(const float4*)&As[kk][(ty<<3)+4];
      *(float4*)&bv[0] = *(const float4*)(Bc + kk*TN + (tx<<2));
      if (TN==128) *(float4*)&bv[4] = *(const float4*)(Bc + kk*TN + 64 + (tx<<2));
#pragma unroll
      for(int i=0;i<8;i++)
#pragma unroll
        for(int j=0;j<NJ;j++) acc[i][j] += av[i]*bv[j];
    }
    __syncthreads();                      // compute done; next A ds_write safe
    if (more){
      const int kk0 = ah<<3;
      As[kk0+0][arow]=a0.x; As[kk0+1][arow]=a0.y; As[kk0+2][arow]=a0.z; As[kk0+3][arow]=a0.w;
      As[kk0+4][arow]=a1.x; As[kk0+5][arow]=a1.y; As[kk0+6][arow]=a1.z; As[kk0+7][arow]=a1.w;
    }
  }
#undef STAGE_B
  // epilogue: rows bm+ty*8+i; cols {bn+tx*4} and (TN=128) {bn+64+tx*4}
  const int c0 = bn + (tx<<2), c1 = c0 + 64;
  float4 bias0 = make_float4(0,0,0,0), bias1 = make_float4(0,0,0,0);
  if (bias){
    bias0 = *(const float4*)&bias[c0];
    if (TN==128) bias1 = *(const float4*)&bias[c1];
  }
#pragma unroll
  for(int i=0;i<8;i++){
    const int row = bm + (ty<<3) + i;
    if (row < Mn){
      float v[NJ];
      v[0]=acc[i][0]+bias0.x; v[1]=acc[i][1]+bias0.y; v[2]=acc[i][2]+bias0.z; v[3]=acc[i][3]+bias0.w;
      if (TN==128){ v[4]=acc[i][4]+bias1.x; v[5]=acc[i][5]+bias1.y; v[6]=acc[i][6]+bias1.z; v[7]=acc[i][7]+bias1.w; }
#pragma unroll
      for(int j=0;j<NJ;j++){
        if (ACT==1) v[j] = tanhf(v[j]);
        if (ACT==2) v[j] = 0.5f*v[j]*(1.0f+erff(v[j]*0.70710678118654752f));
      }
      float* p0 = Cout + (size_t)row*ldC + c0;
      float4 w0 = make_float4(v[0],v[1],v[2],v[3]);
      if (ACCUM){
        float4 o0 = *(const float4*)p0;
        w0.x+=o0.x; w0.y+=o0.y; w0.z+=o0.z; w0.w+=o0.w;
      }
      *(float4*)p0 = w0;
      if (TN==128){
        float* p1 = Cout + (size_t)row*ldC + c1;
        float4 w1 = make_float4(v[4],v[5],v[6],v[7]);
        if (ACCUM){
          float4 o1 = *(const float4*)p1;
          w1.x+=o1.x; w1.y+=o1.y; w1.z+=o1.z; w1.w+=o1.w;
        }
        *(float4*)p1 = w1;
      }
    }
  }
}

// ---------------- attention: block per (b,head); lane-per-query 1-pass flash ----------------
__global__ __launch_bounds__(256) void k_attn(const float* __restrict__ qkv,
    const float* __restrict__ mem, const float* __restrict__ gate,
    float* __restrict__ y){
  __shared__ float ks[KV*50];
  __shared__ float vs[KV*50];
  const int b = blockIdx.x >> 3, hh = blockIdx.x & 7;
  const int tid = threadIdx.x;
  for(int idx=tid; idx<KV*24; idx+=256){
    int j = idx/24, f = (idx - j*24)*2;
    float2 kvv, vvv;
    if (j < MM){
      kvv = *(const float2*)(mem + j*C + hh*HD + f);
      vvv = kvv;
    } else {
      const float* row = qkv + (size_t)(b*TT + j - MM)*N3C + hh*HD + f;
      kvv = *(const float2*)(row + C);
      vvv = *(const float2*)(row + 2*C);
    }
    *(float2*)(ks + j*50 + f) = kvv;
    *(float2*)(vs + j*50 + f) = vvv;
  }
  __syncthreads();
  const int i = tid;
  const float* qrow = qkv + (size_t)(b*TT+i)*N3C + hh*HD;
  float q[HD];
#pragma unroll
  for(int d2=0; d2<24; d2++){
    float2 qv = *(const float2*)(qrow + d2*2);
    q[d2*2] = qv.x; q[d2*2+1] = qv.y;
  }
  float m = -1e30f, l = 0.f;
  float acc[HD];
#pragma unroll
  for(int d=0;d<HD;d++) acc[d]=0.f;

#define ATT_STEP(JROW) {                                            \
    const float* kr = ks + (JROW)*50;                               \
    float dot = 0.f;                                                \
    _Pragma("unroll")                                               \
    for(int d2=0; d2<24; d2++){                                     \
      float2 kv2 = *(const float2*)(kr + d2*2);                     \
      dot += q[d2*2]*kv2.x + q[d2*2+1]*kv2.y;                       \
    }                                                               \
    float s = dot*SCALE_QK;                                         \
    if (s > m + 8.f){                                               \
      float f_ = __expf(m - s);                                     \
      l *= f_;                                                      \
      _Pragma("unroll")                                             \
      for(int d=0; d<HD; d++) acc[d] *= f_;                         \
      m = s;                                                        \
    }                                                               \
    float pch = __expf(s - m);                                      \
    l += pch;                                                       \
    const float* vr = vs + (JROW)*50;                               \
    _Pragma("unroll")                                               \
    for(int d2=0; d2<24; d2++){                                     \
      float2 vv2 = *(const float2*)(vr + d2*2);                     \
      acc[d2*2]   += pch*vv2.x;                                     \
      acc[d2*2+1] += pch*vv2.y;                                     \
    }                                                               \
  }

  for(int j=0; j<MM; j++) ATT_STEP(j)
  const int lo = (i > WIN) ? (i - WIN) : 0;
  for(int j=MM+lo; j<=MM+i; j++) ATT_STEP(j)
#undef ATT_STEP

  const float inv = 1.f/l;
  const float* g = gate + hh*HD;
  float* yr = y + (size_t)(b*TT+i)*C + hh*HD;
#pragma unroll
  for(int d=0;d<HD;d++) yr[d] = acc[d]*inv*g[d];
}

// ---------------- router ----------------
__global__ void k_gate(const float* __restrict__ h2, const float* __restrict__ gw,
                       const float* __restrict__ gb, float* __restrict__ wout){
  int row = blockIdx.x*4 + (threadIdx.x>>6);
  int lane = threadIdx.x & 63;
  const float* hr = h2 + (size_t)row*C;
  float a0=0,a1=0,a2=0,a3=0;
  for(int c=lane;c<C;c+=64){
    float hv = hr[c];
    const float* g = gw + c*NE;
    a0+=hv*g[0]; a1+=hv*g[1]; a2+=hv*g[2]; a3+=hv*g[3];
  }
  a0=wsum(a0); a1=wsum(a1); a2=wsum(a2); a3=wsum(a3);
  if (lane==0){
    float p[4]={a0+gb[0],a1+gb[1],a2+gb[2],a3+gb[3]};
    float m = fmaxf(fmaxf(p[0],p[1]),fmaxf(p[2],p[3]));
    float s=0.f;
#pragma unroll
    for(int e=0;e<4;e++){ p[e]=expf(p[e]-m); s+=p[e]; }
#pragma unroll
    for(int e=0;e<4;e++) p[e] /= s;
    int i1=0;
    for(int e=1;e<4;e++) if(p[e]>p[i1]) i1=e;
    int i2=-1;
    for(int e=0;e<4;e++){ if(e==i1) continue; if(i2<0 || p[e]>p[i2]) i2=e; }
    float invs = 1.f/(p[i1]+p[i2]+1e-9f);
    float wv[4]={0.f,0.f,0.f,0.f};
    wv[i1]=p[i1]*invs; wv[i2]=p[i2]*invs;
    float* o = wout + (size_t)row*NE;
    o[0]=wv[0]; o[1]=wv[1]; o[2]=wv[2]; o[3]=wv[3];
  }
}

// ---------------- per-expert compaction + inverse map ----------------
__global__ __launch_bounds__(256) void k_compact(const float* __restrict__ wbuf,
    int* __restrict__ ridx, int* __restrict__ posmap, int* __restrict__ cnt){
  int e = blockIdx.x;
  int tid = threadIdx.x;
  int wave = tid>>6, lane = tid&63;
  __shared__ int wsum_s[4];
  __shared__ int base_s;
  if (tid==0) base_s = 0;
  __syncthreads();
  for(int t0=0; t0<NT; t0+=256){
    int t = t0 + tid;
    bool f = wbuf[(size_t)t*NE + e] > 0.f;
    unsigned long long bal = __ballot(f);
    int pre = __popcll(bal & ((1ull<<lane)-1ull));
    if (lane==0) wsum_s[wave] = __popcll(bal);
    __syncthreads();
    int off = 0;
#pragma unroll
    for(int w2=0;w2<4;w2++) if (w2 < wave) off += wsum_s[w2];
    int tot = wsum_s[0]+wsum_s[1]+wsum_s[2]+wsum_s[3];
    int b0 = base_s;
    int pos = b0 + off + pre;
    if (f) ridx[(size_t)e*NT + pos] = t;
    posmap[(size_t)t*NE + e] = f ? pos : -1;
    __syncthreads();
    if (tid==0) base_s = b0 + tot;
    __syncthreads();
  }
  if (tid==0) cnt[e] = base_s;
}

// ---------------- MoE gather ----------------
__global__ __launch_bounds__(256) void k_moe_gather(const float* __restrict__ ye,
    const float* __restrict__ wbuf, const int* __restrict__ posmap,
    const int* __restrict__ cnt, float* __restrict__ x){
  int idx = blockIdx.x*256 + threadIdx.x;
  if (idx >= NT*(C/4)) return;
  int eb[NE]; int s=0;
#pragma unroll
  for(int e=0;e<NE;e++){ eb[e]=s; s+=cnt[e]; }
  int t = idx/(C/4), c4 = (idx - t*(C/4))*4;
  float4 acc = *(const float4*)(x + (size_t)t*C + c4);
#pragma unroll
  for(int e=0;e<NE;e++){
    int p = posmap[(size_t)t*NE + e];
    if (p >= 0){
      float w = wbuf[(size_t)t*NE + e];
      float4 yv = *(const float4*)(ye + (size_t)(eb[e]+p)*C + c4);
      acc.x += w*yv.x; acc.y += w*yv.y; acc.z += w*yv.z; acc.w += w*yv.w;
    }
  }
  *(float4*)(x + (size_t)t*C + c4) = acc;
}

extern "C" void kernel_launch(void* const* d_in, const int* in_sizes, int n_in,
                              void* d_out, int out_size, void* d_ws, size_t ws_size,
                              hipStream_t stream){
  (void)in_sizes; (void)n_in; (void)out_size; (void)ws_size;
  const int*   tokens  = (const int*)d_in[0];
  const float* tok_emb = (const float*)d_in[1];
  const float* pos_emb = (const float*)d_in[2];
  const float* mem     = (const float*)d_in[3];
  const float* ln1_w   = (const float*)d_in[4];
  const float* ln1_b   = (const float*)d_in[5];
  const float* qkv_w   = (const float*)d_in[6];
  const float* qkv_b   = (const float*)d_in[7];
  const float* proj_w  = (const float*)d_in[8];
  const float* proj_b  = (const float*)d_in[9];
  const float* attn_g  = (const float*)d_in[10];
  const float* th1_w   = (const float*)d_in[11];
  const float* th1_b   = (const float*)d_in[12];
  const float* th2_w   = (const float*)d_in[13];
  const float* th2_b   = (const float*)d_in[14];
  const float* ln2_w   = (const float*)d_in[15];
  const float* ln2_b   = (const float*)d_in[16];
  const float* gate_w  = (const float*)d_in[17];
  const float* gate_b  = (const float*)d_in[18];
  const float* e1_w    = (const float*)d_in[19];
  const float* e1_b    = (const float*)d_in[20];
  const float* e2_w    = (const float*)d_in[21];
  const float* e2_b    = (const float*)d_in[22];
  const float* lnf_w   = (const float*)d_in[23];
  const float* lnf_b   = (const float*)d_in[24];
  const float* head_w  = (const float*)d_in[25];
  const float* head_b  = (const float*)d_in[26];
  float* out = (float*)d_out;

  char* p = (char*)d_ws;
  float* x    = (float*)p; p += (size_t)NT*C*4;       // residual
  float* h    = (float*)p; p += (size_t)NT*C*4;       // LN out
  char*  rb   = p;                                     // shared region
  float* qkvb = (float*)rb;                            // qkv   [0, 75.5MB)
  float* sh   = (float*)(rb + (size_t)NT*N3C*4);       // y/t1  [75.5, 109MB)
  p += (size_t)NT*N3C*4 + (size_t)NT*TD*4*2;
  float* wbuf = (float*)p; p += (size_t)NT*NE*4;
  int*   ridx = (int*)p;   p += (size_t)NE*NT*4;
  int*   posm = (int*)p;   p += (size_t)NT*NE*4;
  int*   cnt  = (int*)p;   p += 64;
  float* he   = (float*)rb;                            // [0, 50.3MB)   (MoE phase)
  float* ye   = (float*)(rb + (size_t)2*NT*FCH*4);     // [50.3, 100.6) (MoE phase)

  dim3 b256(256);
  k_embed<<<dim3((NT*C+255)/256), b256, 0, stream>>>(tokens, tok_emb, pos_emb, x);
  for(int l=0;l<LAYERS;l++){
    k_ln<<<dim3(NT/4), b256, 0, stream>>>(x, ln1_w+l*C, ln1_b+l*C, h);
    k_gemm<0,false,false,false,128><<<dim3(N3C/128, NT/128), b256, 0, stream>>>(
        h, qkv_w+(size_t)l*C*N3C, qkv_b+(size_t)l*N3C, nullptr, nullptr, 0, 0,
        qkvb, C, C, N3C, N3C);
    k_attn<<<dim3(BB*NH), b256, 0, stream>>>(qkvb, mem, attn_g+(size_t)l*C, sh);
    k_gemm<0,true,false,false,64><<<dim3(C/64, NT/128), b256, 0, stream>>>(
        sh, proj_w+(size_t)l*C*C, proj_b+(size_t)l*C, nullptr, nullptr, 0, 0,
        x, C, C, C, C);
    k_gemm<1,false,false,false,64><<<dim3(TD/64, NT/128), b256, 0, stream>>>(
        x, th1_w+(size_t)l*C*TD, th1_b+(size_t)l*TD, nullptr, nullptr, 0, 0,
        sh, C, C, TD, TD);
    k_gemm<0,true,false,false,64><<<dim3(C/64, NT/128), b256, 0, stream>>>(
        sh, th2_w+(size_t)l*TD*C, th2_b+(size_t)l*C, nullptr, nullptr, 0, 0,
        x, TD, TD, C, C);
    k_ln<<<dim3(NT/4), b256, 0, stream>>>(x, ln2_w+l*C, ln2_b+l*C, h);
    k_gate<<<dim3(NT/4), b256, 0, stream>>>(h, gate_w+(size_t)l*C*NE, gate_b+(size_t)l*NE, wbuf);
    k_compact<<<dim3(NE), b256, 0, stream>>>(wbuf, ridx, posm, cnt);
    for(int f0=0; f0<FF; f0+=FCH){
      k_gemm<2,false,true,true,128><<<dim3(FCH/128, NT/128, NE), b256, 0, stream>>>(
          h, e1_w + (size_t)l*NE*C*FF + f0, e1_b + (size_t)l*NE*FF + f0,
          ridx, cnt, (size_t)C*FF, (size_t)FF,
          he, C, C, FF, FCH);
      if (f0==0)
        k_gemm<0,false,true,false,128><<<dim3(C/128, NT/128, NE), b256, 0, stream>>>(
            he, e2_w + (size_t)l*NE*FF*C, e2_b + (size_t)l*NE*C,
            nullptr, cnt, (size_t)FF*C, (size_t)C,
            ye, FCH, FCH, C, C);
      else
        k_gemm<0,true,true,false,128><<<dim3(C/128, NT/128, NE), b256, 0, stream>>>(
            he, e2_w + (size_t)l*NE*FF*C + (size_t)f0*C, nullptr,
            nullptr, cnt, (size_t)FF*C, (size_t)C,
            ye, FCH, FCH, C, C);
    }
    k_moe_gather<<<dim3((NT*(C/4)+255)/256), b256, 0, stream>>>(ye, wbuf, posm, cnt, x);
  }
  k_ln<<<dim3(NT/4), b256, 0, stream>>>(x, lnf_w, lnf_b, h);
  k_gemm<0,false,false,false,64><<<dim3(NV/64, NT/128), b256, 0, stream>>>(
      h, head_w, head_b, nullptr, nullptr, 0, 0,
      out, C, C, NV, NV);
}

// Round 11
// 14165.404 us; speedup vs baseline: 15.6441x; 1.5761x over previous
//
#include <hip/hip_runtime.h>
#include <math.h>

#define LAYERS 8
#define C 384
#define NH 8
#define NE 4
#define TD 256
#define NV 256
#define WIN 64
#define MM 56
#define HD 48
#define BB 64
#define TT 256
#define NT (BB*TT)
#define N3C 1152
#define FF 1536
#define KV 312
#define FCH 384              // MoE FF chunk width
#define SCALE_QK 0.14433756729740643f

static __device__ __forceinline__ float wsum(float v){
#pragma unroll
  for(int o=32;o;o>>=1) v += __shfl_xor(v,o);
  return v;
}

// ---------------- embed ----------------
__global__ void k_embed(const int* __restrict__ tokens, const float* __restrict__ tok_emb,
                        const float* __restrict__ pos_emb, float* __restrict__ x){
  int idx = blockIdx.x*256 + threadIdx.x;
  if (idx >= NT*C) return;
  int t = idx / C, c = idx - t*C;
  x[idx] = tok_emb[tokens[t]*C + c] + pos_emb[(t % TT)*C + c];
}

// ---------------- layernorm (wave per row) ----------------
__global__ void k_ln(const float* __restrict__ in, const float* __restrict__ w,
                     const float* __restrict__ b, float* __restrict__ out){
  int row = blockIdx.x*4 + (threadIdx.x>>6);
  int lane = threadIdx.x & 63;
  const float* xr = in + (size_t)row*C;
  float v[6]; float s = 0.f;
#pragma unroll
  for(int i=0;i<6;i++){ v[i]=xr[lane+64*i]; s+=v[i]; }
  s = wsum(s);
  float mu = s*(1.f/C);
  float q=0.f;
#pragma unroll
  for(int i=0;i<6;i++){ float d=v[i]-mu; q+=d*d; }
  q = wsum(q);
  float inv = rsqrtf(q*(1.f/C)+1e-5f);
  float* orow = out + (size_t)row*C;
#pragma unroll
  for(int i=0;i<6;i++){ int c=lane+64*i; orow[c] = (v[i]-mu)*inv*w[c]+b[c]; }
}

// ---------------- fp32 GEMM: 128xTN tile, BK=16, 256 thr ----------------
// ROUND-6 PROVEN CODEGEN (84 VGPR @ TN=128): single LDS buffer, register
// prefetch issued immediately AFTER the barrier so the pre-barrier vmcnt(0)
// drain lands after ~2048 cycles of FMA. DO NOT: double-buffer LDS, raise BK,
// add launch_bounds min-waves, or gload_lds here — all four ballooned VGPR to
// 184-256 and regressed 1.4-15x (rounds 7-10).
// MOE: blockIdx.z = expert; Mn=cnt[z]; W/bias += z*stride; C rows offset ebase[z];
//      GATHER: A rows via ridx[z*NT + r]; else A rows offset by ebase[z].
// ACT: 0 none, 1 tanh, 2 exact gelu
template<int ACT, bool ACCUM, bool MOE, bool GATHER, int TN>
__global__ __launch_bounds__(256) void k_gemm(
    const float* __restrict__ A, const float* __restrict__ W,
    const float* __restrict__ bias,
    const int* __restrict__ ridx, const int* __restrict__ cnt,
    size_t sWz, size_t sBz,
    float* __restrict__ Cout, int Kn, int ldA, int ldB, int ldC)
{
  const int z = MOE ? (int)blockIdx.z : 0;
  int Mn = NT;
  if (MOE){
    int eb = 0;
#pragma unroll
    for(int i=0;i<NE;i++){ int ci = cnt[i]; if (i<z) eb += ci; if (i==z) Mn = ci; }
    W += (size_t)z*sWz;
    if (bias) bias += (size_t)z*sBz;
    if (!GATHER) A += (size_t)eb*ldA;
    Cout += (size_t)eb*ldC;
  }
  const int bm = (int)blockIdx.y<<7, bn = (int)blockIdx.x*TN;
  if (bm >= Mn) return;
  __shared__ __attribute__((aligned(16))) float As[16][132];
  __shared__ __attribute__((aligned(16))) float Bs[16][TN+4];
  const int tid = threadIdx.x;
  const int tx = tid&15, ty = tid>>4;
  const int arow = tid>>1, ah = tid&1;
  const int brow = tid>>4;
  const int bc = (TN==128) ? ((tid&15)<<3) : ((tid&15)<<2);
  int r0 = bm + arow; if (r0 >= Mn) r0 = Mn-1;
  const int agr = GATHER ? ridx[(size_t)z*NT + r0] : r0;
  const float* Arow = A + (size_t)agr*ldA + (ah<<3);
  const float* Wrow = W + (size_t)brow*ldB + bn + bc;
  float4 a0 = *(const float4*)(Arow);
  float4 a1 = *(const float4*)(Arow+4);
  float4 b0 = *(const float4*)(Wrow);
  float4 b1;
  if (TN==128) b1 = *(const float4*)(Wrow+4);
  {
    const int kk0 = ah<<3;
    As[kk0+0][arow]=a0.x; As[kk0+1][arow]=a0.y; As[kk0+2][arow]=a0.z; As[kk0+3][arow]=a0.w;
    As[kk0+4][arow]=a1.x; As[kk0+5][arow]=a1.y; As[kk0+6][arow]=a1.z; As[kk0+7][arow]=a1.w;
    *(float4*)&Bs[brow][bc] = b0;
    if (TN==128) *(float4*)&Bs[brow][bc+4] = b1;
  }
  constexpr int NJ = (TN==128)?8:4;
  float acc[8][NJ] = {};
  for (int k0=0; k0<Kn; k0+=16){
    __syncthreads();                       // tile k0 visible in LDS
    const bool more = (k0+16 < Kn);
    if (more){                             // issue next-tile loads AFTER barrier
      a0 = *(const float4*)(Arow + k0+16);
      a1 = *(const float4*)(Arow + k0+20);
      b0 = *(const float4*)(Wrow + (size_t)(k0+16)*ldB);
      if (TN==128) b1 = *(const float4*)(Wrow + (size_t)(k0+16)*ldB + 4);
    }
#pragma unroll
    for (int kk=0;kk<16;kk++){
      float av[8], bv[NJ];
      *(float4*)&av[0] = *(const float4*)&As[kk][ty<<3];
      *(float4*)&av[4] = *(const float4*)&As[kk][(ty<<3)+4];
      *(float4*)&bv[0] = *(const float4*)&Bs[kk][tx<<2];
      if (TN==128) *(float4*)&bv[4] = *(const float4*)&Bs[kk][64+(tx<<2)];
#pragma unroll
      for(int i=0;i<8;i++)
#pragma unroll
        for(int j=0;j<NJ;j++) acc[i][j] += av[i]*bv[j];
    }
    __syncthreads();                       // compute done; vmcnt drain hidden
    if (more){
      const int kk0 = ah<<3;
      As[kk0+0][arow]=a0.x; As[kk0+1][arow]=a0.y; As[kk0+2][arow]=a0.z; As[kk0+3][arow]=a0.w;
      As[kk0+4][arow]=a1.x; As[kk0+5][arow]=a1.y; As[kk0+6][arow]=a1.z; As[kk0+7][arow]=a1.w;
      *(float4*)&Bs[brow][bc] = b0;
      if (TN==128) *(float4*)&Bs[brow][bc+4] = b1;
    }
  }
  // epilogue: rows bm+ty*8+i; cols {bn+tx*4} and (TN=128) {bn+64+tx*4}
  const int c0 = bn + (tx<<2), c1 = c0 + 64;
  float4 bias0 = make_float4(0,0,0,0), bias1 = make_float4(0,0,0,0);
  if (bias){
    bias0 = *(const float4*)&bias[c0];
    if (TN==128) bias1 = *(const float4*)&bias[c1];
  }
#pragma unroll
  for(int i=0;i<8;i++){
    const int row = bm + (ty<<3) + i;
    if (row < Mn){
      float v[NJ];
      v[0]=acc[i][0]+bias0.x; v[1]=acc[i][1]+bias0.y; v[2]=acc[i][2]+bias0.z; v[3]=acc[i][3]+bias0.w;
      if (TN==128){ v[4]=acc[i][4]+bias1.x; v[5]=acc[i][5]+bias1.y; v[6]=acc[i][6]+bias1.z; v[7]=acc[i][7]+bias1.w; }
#pragma unroll
      for(int j=0;j<NJ;j++){
        if (ACT==1) v[j] = tanhf(v[j]);
        if (ACT==2) v[j] = 0.5f*v[j]*(1.0f+erff(v[j]*0.70710678118654752f));
      }
      float* p0 = Cout + (size_t)row*ldC + c0;
      float4 w0 = make_float4(v[0],v[1],v[2],v[3]);
      if (ACCUM){
        float4 o0 = *(const float4*)p0;
        w0.x+=o0.x; w0.y+=o0.y; w0.z+=o0.z; w0.w+=o0.w;
      }
      *(float4*)p0 = w0;
      if (TN==128){
        float* p1 = Cout + (size_t)row*ldC + c1;
        float4 w1 = make_float4(v[4],v[5],v[6],v[7]);
        if (ACCUM){
          float4 o1 = *(const float4*)p1;
          w1.x+=o1.x; w1.y+=o1.y; w1.z+=o1.z; w1.w+=o1.w;
        }
        *(float4*)p1 = w1;
      }
    }
  }
}

// ---------------- attention: block per (b,head); lane-per-query 1-pass flash ----------------
__global__ __launch_bounds__(256) void k_attn(const float* __restrict__ qkv,
    const float* __restrict__ mem, const float* __restrict__ gate,
    float* __restrict__ y){
  __shared__ float ks[KV*50];
  __shared__ float vs[KV*50];
  const int b = blockIdx.x >> 3, hh = blockIdx.x & 7;
  const int tid = threadIdx.x;
  for(int idx=tid; idx<KV*24; idx+=256){
    int j = idx/24, f = (idx - j*24)*2;
    float2 kvv, vvv;
    if (j < MM){
      kvv = *(const float2*)(mem + j*C + hh*HD + f);
      vvv = kvv;
    } else {
      const float* row = qkv + (size_t)(b*TT + j - MM)*N3C + hh*HD + f;
      kvv = *(const float2*)(row + C);
      vvv = *(const float2*)(row + 2*C);
    }
    *(float2*)(ks + j*50 + f) = kvv;
    *(float2*)(vs + j*50 + f) = vvv;
  }
  __syncthreads();
  const int i = tid;
  const float* qrow = qkv + (size_t)(b*TT+i)*N3C + hh*HD;
  float q[HD];
#pragma unroll
  for(int d2=0; d2<24; d2++){
    float2 qv = *(const float2*)(qrow + d2*2);
    q[d2*2] = qv.x; q[d2*2+1] = qv.y;
  }
  float m = -1e30f, l = 0.f;
  float acc[HD];
#pragma unroll
  for(int d=0;d<HD;d++) acc[d]=0.f;

#define ATT_STEP(JROW) {                                            \
    const float* kr = ks + (JROW)*50;                               \
    float dot = 0.f;                                                \
    _Pragma("unroll")                                               \
    for(int d2=0; d2<24; d2++){                                     \
      float2 kv2 = *(const float2*)(kr + d2*2);                     \
      dot += q[d2*2]*kv2.x + q[d2*2+1]*kv2.y;                       \
    }                                                               \
    float s = dot*SCALE_QK;                                         \
    if (s > m + 8.f){                                               \
      float f_ = __expf(m - s);                                     \
      l *= f_;                                                      \
      _Pragma("unroll")                                             \
      for(int d=0; d<HD; d++) acc[d] *= f_;                         \
      m = s;                                                        \
    }                                                               \
    float pch = __expf(s - m);                                      \
    l += pch;                                                       \
    const float* vr = vs + (JROW)*50;                               \
    _Pragma("unroll")                                               \
    for(int d2=0; d2<24; d2++){                                     \
      float2 vv2 = *(const float2*)(vr + d2*2);                     \
      acc[d2*2]   += pch*vv2.x;                                     \
      acc[d2*2+1] += pch*vv2.y;                                     \
    }                                                               \
  }

  for(int j=0; j<MM; j++) ATT_STEP(j)
  const int lo = (i > WIN) ? (i - WIN) : 0;
  for(int j=MM+lo; j<=MM+i; j++) ATT_STEP(j)
#undef ATT_STEP

  const float inv = 1.f/l;
  const float* g = gate + hh*HD;
  float* yr = y + (size_t)(b*TT+i)*C + hh*HD;
#pragma unroll
  for(int d=0;d<HD;d++) yr[d] = acc[d]*inv*g[d];
}

// ---------------- router ----------------
__global__ void k_gate(const float* __restrict__ h2, const float* __restrict__ gw,
                       const float* __restrict__ gb, float* __restrict__ wout){
  int row = blockIdx.x*4 + (threadIdx.x>>6);
  int lane = threadIdx.x & 63;
  const float* hr = h2 + (size_t)row*C;
  float a0=0,a1=0,a2=0,a3=0;
  for(int c=lane;c<C;c+=64){
    float hv = hr[c];
    const float* g = gw + c*NE;
    a0+=hv*g[0]; a1+=hv*g[1]; a2+=hv*g[2]; a3+=hv*g[3];
  }
  a0=wsum(a0); a1=wsum(a1); a2=wsum(a2); a3=wsum(a3);
  if (lane==0){
    float p[4]={a0+gb[0],a1+gb[1],a2+gb[2],a3+gb[3]};
    float m = fmaxf(fmaxf(p[0],p[1]),fmaxf(p[2],p[3]));
    float s=0.f;
#pragma unroll
    for(int e=0;e<4;e++){ p[e]=expf(p[e]-m); s+=p[e]; }
#pragma unroll
    for(int e=0;e<4;e++) p[e] /= s;
    int i1=0;
    for(int e=1;e<4;e++) if(p[e]>p[i1]) i1=e;
    int i2=-1;
    for(int e=0;e<4;e++){ if(e==i1) continue; if(i2<0 || p[e]>p[i2]) i2=e; }
    float invs = 1.f/(p[i1]+p[i2]+1e-9f);
    float wv[4]={0.f,0.f,0.f,0.f};
    wv[i1]=p[i1]*invs; wv[i2]=p[i2]*invs;
    float* o = wout + (size_t)row*NE;
    o[0]=wv[0]; o[1]=wv[1]; o[2]=wv[2]; o[3]=wv[3];
  }
}

// ---------------- per-expert compaction + inverse map ----------------
__global__ __launch_bounds__(256) void k_compact(const float* __restrict__ wbuf,
    int* __restrict__ ridx, int* __restrict__ posmap, int* __restrict__ cnt){
  int e = blockIdx.x;
  int tid = threadIdx.x;
  int wave = tid>>6, lane = tid&63;
  __shared__ int wsum_s[4];
  __shared__ int base_s;
  if (tid==0) base_s = 0;
  __syncthreads();
  for(int t0=0; t0<NT; t0+=256){
    int t = t0 + tid;
    bool f = wbuf[(size_t)t*NE + e] > 0.f;
    unsigned long long bal = __ballot(f);
    int pre = __popcll(bal & ((1ull<<lane)-1ull));
    if (lane==0) wsum_s[wave] = __popcll(bal);
    __syncthreads();
    int off = 0;
#pragma unroll
    for(int w2=0;w2<4;w2++) if (w2 < wave) off += wsum_s[w2];
    int tot = wsum_s[0]+wsum_s[1]+wsum_s[2]+wsum_s[3];
    int b0 = base_s;
    int pos = b0 + off + pre;
    if (f) ridx[(size_t)e*NT + pos] = t;
    posmap[(size_t)t*NE + e] = f ? pos : -1;
    __syncthreads();
    if (tid==0) base_s = b0 + tot;
    __syncthreads();
  }
  if (tid==0) cnt[e] = base_s;
}

// ---------------- MoE gather: x[t] += sum_e w[t,e] * ye[ebase[e]+pos(t,e)] ----------------
__global__ __launch_bounds__(256) void k_moe_gather(const float* __restrict__ ye,
    const float* __restrict__ wbuf, const int* __restrict__ posmap,
    const int* __restrict__ cnt, float* __restrict__ x){
  int idx = blockIdx.x*256 + threadIdx.x;
  if (idx >= NT*(C/4)) return;
  int eb[NE]; int s=0;
#pragma unroll
  for(int e=0;e<NE;e++){ eb[e]=s; s+=cnt[e]; }
  int t = idx/(C/4), c4 = (idx - t*(C/4))*4;
  float4 acc = *(const float4*)(x + (size_t)t*C + c4);
#pragma unroll
  for(int e=0;e<NE;e++){
    int p = posmap[(size_t)t*NE + e];
    if (p >= 0){
      float w = wbuf[(size_t)t*NE + e];
      float4 yv = *(const float4*)(ye + (size_t)(eb[e]+p)*C + c4);
      acc.x += w*yv.x; acc.y += w*yv.y; acc.z += w*yv.z; acc.w += w*yv.w;
    }
  }
  *(float4*)(x + (size_t)t*C + c4) = acc;
}

extern "C" void kernel_launch(void* const* d_in, const int* in_sizes, int n_in,
                              void* d_out, int out_size, void* d_ws, size_t ws_size,
                              hipStream_t stream){
  (void)in_sizes; (void)n_in; (void)out_size; (void)ws_size;
  const int*   tokens  = (const int*)d_in[0];
  const float* tok_emb = (const float*)d_in[1];
  const float* pos_emb = (const float*)d_in[2];
  const float* mem     = (const float*)d_in[3];
  const float* ln1_w   = (const float*)d_in[4];
  const float* ln1_b   = (const float*)d_in[5];
  const float* qkv_w   = (const float*)d_in[6];
  const float* qkv_b   = (const float*)d_in[7];
  const float* proj_w  = (const float*)d_in[8];
  const float* proj_b  = (const float*)d_in[9];
  const float* attn_g  = (const float*)d_in[10];
  const float* th1_w   = (const float*)d_in[11];
  const float* th1_b   = (const float*)d_in[12];
  const float* th2_w   = (const float*)d_in[13];
  const float* th2_b   = (const float*)d_in[14];
  const float* ln2_w   = (const float*)d_in[15];
  const float* ln2_b   = (const float*)d_in[16];
  const float* gate_w  = (const float*)d_in[17];
  const float* gate_b  = (const float*)d_in[18];
  const float* e1_w    = (const float*)d_in[19];
  const float* e1_b    = (const float*)d_in[20];
  const float* e2_w    = (const float*)d_in[21];
  const float* e2_b    = (const float*)d_in[22];
  const float* lnf_w   = (const float*)d_in[23];
  const float* lnf_b   = (const float*)d_in[24];
  const float* head_w  = (const float*)d_in[25];
  const float* head_b  = (const float*)d_in[26];
  float* out = (float*)d_out;

  char* p = (char*)d_ws;
  float* x    = (float*)p; p += (size_t)NT*C*4;       // residual
  float* h    = (float*)p; p += (size_t)NT*C*4;       // LN out
  char*  rb   = p;                                     // shared region (109 MB)
  float* qkvb = (float*)rb;                            // qkv   [0, 75.5MB)
  float* sh   = (float*)(rb + (size_t)NT*N3C*4);       // y/t1  [75.5, 109MB)
  p += (size_t)NT*N3C*4 + (size_t)NT*TD*4*2;
  float* wbuf = (float*)p; p += (size_t)NT*NE*4;
  int*   ridx = (int*)p;   p += (size_t)NE*NT*4;
  int*   posm = (int*)p;   p += (size_t)NT*NE*4;
  int*   cnt  = (int*)p;   p += 64;
  float* he   = (float*)rb;                            // [0, 50.3MB)   (MoE phase; 2NT x FCH)
  float* ye   = (float*)(rb + (size_t)2*NT*FCH*4);     // [50.3, 100.6) (MoE phase; 2NT x C)

  dim3 b256(256);
  k_embed<<<dim3((NT*C+255)/256), b256, 0, stream>>>(tokens, tok_emb, pos_emb, x);
  for(int l=0;l<LAYERS;l++){
    k_ln<<<dim3(NT/4), b256, 0, stream>>>(x, ln1_w+l*C, ln1_b+l*C, h);
    k_gemm<0,false,false,false,128><<<dim3(N3C/128, NT/128), b256, 0, stream>>>(
        h, qkv_w+(size_t)l*C*N3C, qkv_b+(size_t)l*N3C, nullptr, nullptr, 0, 0,
        qkvb, C, C, N3C, N3C);
    k_attn<<<dim3(BB*NH), b256, 0, stream>>>(qkvb, mem, attn_g+(size_t)l*C, sh);
    k_gemm<0,true,false,false,64><<<dim3(C/64, NT/128), b256, 0, stream>>>(
        sh, proj_w+(size_t)l*C*C, proj_b+(size_t)l*C, nullptr, nullptr, 0, 0,
        x, C, C, C, C);
    k_gemm<1,false,false,false,64><<<dim3(TD/64, NT/128), b256, 0, stream>>>(
        x, th1_w+(size_t)l*C*TD, th1_b+(size_t)l*TD, nullptr, nullptr, 0, 0,
        sh, C, C, TD, TD);
    k_gemm<0,true,false,false,64><<<dim3(C/64, NT/128), b256, 0, stream>>>(
        sh, th2_w+(size_t)l*TD*C, th2_b+(size_t)l*C, nullptr, nullptr, 0, 0,
        x, TD, TD, C, C);
    k_ln<<<dim3(NT/4), b256, 0, stream>>>(x, ln2_w+l*C, ln2_b+l*C, h);
    k_gate<<<dim3(NT/4), b256, 0, stream>>>(h, gate_w+(size_t)l*C*NE, gate_b+(size_t)l*NE, wbuf);
    k_compact<<<dim3(NE), b256, 0, stream>>>(wbuf, ridx, posm, cnt);
    for(int f0=0; f0<FF; f0+=FCH){
      // he = gelu(h[sel] @ e1[:, f0:f0+FCH] + e1_b)   (all experts via z)
      k_gemm<2,false,true,true,128><<<dim3(FCH/128, NT/128, NE), b256, 0, stream>>>(
          h, e1_w + (size_t)l*NE*C*FF + f0, e1_b + (size_t)l*NE*FF + f0,
          ridx, cnt, (size_t)C*FF, (size_t)FF,
          he, C, C, FF, FCH);
      // ye (+)= he @ e2[f0:f0+FCH, :] (+ e2_b on first chunk)
      if (f0==0)
        k_gemm<0,false,true,false,128><<<dim3(C/128, NT/128, NE), b256, 0, stream>>>(
            he, e2_w + (size_t)l*NE*FF*C, e2_b + (size_t)l*NE*C,
            nullptr, cnt, (size_t)FF*C, (size_t)C,
            ye, FCH, FCH, C, C);
      else
        k_gemm<0,true,true,false,128><<<dim3(C/128, NT/128, NE), b256, 0, stream>>>(
            he, e2_w + (size_t)l*NE*FF*C + (size_t)f0*C, nullptr,
            nullptr, cnt, (size_t)FF*C, (size_t)C,
            ye, FCH, FCH, C, C);
    }
    k_moe_gather<<<dim3((NT*(C/4)+255)/256), b256, 0, stream>>>(ye, wbuf, posm, cnt, x);
  }
  k_ln<<<dim3(NT/4), b256, 0, stream>>>(x, lnf_w, lnf_b, h);
  k_gemm<0,false,false,false,64><<<dim3(NV/64, NT/128), b256, 0, stream>>>(
      h, head_w, head_b, nullptr, nullptr, 0, 0,
      out, C, C, NV, NV);
}

// Round 12
// 10058.719 us; speedup vs baseline: 22.0311x; 1.4083x over previous
//
#include <hip/hip_runtime.h>
#include <math.h>

#define LAYERS 8
#define C 384
#define NH 8
#define NE 4
#define TD 256
#define NV 256
#define WIN 64
#define MM 56
#define HD 48
#define BB 64
#define TT 256
#define NT (BB*TT)
#define N3C 1152
#define FF 1536
#define KV 312
#define FCH 384              // MoE FF chunk width
#define SCALE_QK 0.14433756729740643f

typedef _Float16 f16;
typedef __attribute__((ext_vector_type(8))) _Float16 f16x8;
typedef __attribute__((ext_vector_type(4))) _Float16 f16x4;
typedef __attribute__((ext_vector_type(4))) float f32x4;

static __device__ __forceinline__ float wsum(float v){
#pragma unroll
  for(int o=32;o;o>>=1) v += __shfl_xor(v,o);
  return v;
}

// ---------------- embed ----------------
__global__ void k_embed(const int* __restrict__ tokens, const float* __restrict__ tok_emb,
                        const float* __restrict__ pos_emb, float* __restrict__ x){
  int idx = blockIdx.x*256 + threadIdx.x;
  if (idx >= NT*C) return;
  int t = idx / C, c = idx - t*C;
  x[idx] = tok_emb[tokens[t]*C + c] + pos_emb[(t % TT)*C + c];
}

// ---------------- layernorm (wave per row) ----------------
__global__ void k_ln(const float* __restrict__ in, const float* __restrict__ w,
                     const float* __restrict__ b, float* __restrict__ out){
  int row = blockIdx.x*4 + (threadIdx.x>>6);
  int lane = threadIdx.x & 63;
  const float* xr = in + (size_t)row*C;
  float v[6]; float s = 0.f;
#pragma unroll
  for(int i=0;i<6;i++){ v[i]=xr[lane+64*i]; s+=v[i]; }
  s = wsum(s);
  float mu = s*(1.f/C);
  float q=0.f;
#pragma unroll
  for(int i=0;i<6;i++){ float d=v[i]-mu; q+=d*d; }
  q = wsum(q);
  float inv = rsqrtf(q*(1.f/C)+1e-5f);
  float* orow = out + (size_t)row*C;
#pragma unroll
  for(int i=0;i<6;i++){ int c=lane+64*i; orow[c] = (v[i]-mu)*inv*w[c]+b[c]; }
}

// ---------------- fp32 GEMM: 128xTN tile, BK=16 (round-6 proven codegen) ----------------
// Used for qkv/proj/th1/th2/head. DO NOT: double-buffer LDS, raise BK, add
// launch_bounds min-waves, or gload_lds — all ballooned VGPR (rounds 7-10).
template<int ACT, bool ACCUM, int TN>
__global__ __launch_bounds__(256) void k_gemm(
    const float* __restrict__ A, const float* __restrict__ W,
    const float* __restrict__ bias,
    float* __restrict__ Cout, int Kn, int ldA, int ldB, int ldC)
{
  const int bm = (int)blockIdx.y<<7, bn = (int)blockIdx.x*TN;
  __shared__ __attribute__((aligned(16))) float As[16][132];
  __shared__ __attribute__((aligned(16))) float Bs[16][TN+4];
  const int tid = threadIdx.x;
  const int tx = tid&15, ty = tid>>4;
  const int arow = tid>>1, ah = tid&1;
  const int brow = tid>>4;
  const int bc = (TN==128) ? ((tid&15)<<3) : ((tid&15)<<2);
  const float* Arow = A + (size_t)(bm+arow)*ldA + (ah<<3);
  const float* Wrow = W + (size_t)brow*ldB + bn + bc;
  float4 a0 = *(const float4*)(Arow);
  float4 a1 = *(const float4*)(Arow+4);
  float4 b0 = *(const float4*)(Wrow);
  float4 b1;
  if (TN==128) b1 = *(const float4*)(Wrow+4);
  {
    const int kk0 = ah<<3;
    As[kk0+0][arow]=a0.x; As[kk0+1][arow]=a0.y; As[kk0+2][arow]=a0.z; As[kk0+3][arow]=a0.w;
    As[kk0+4][arow]=a1.x; As[kk0+5][arow]=a1.y; As[kk0+6][arow]=a1.z; As[kk0+7][arow]=a1.w;
    *(float4*)&Bs[brow][bc] = b0;
    if (TN==128) *(float4*)&Bs[brow][bc+4] = b1;
  }
  constexpr int NJ = (TN==128)?8:4;
  float acc[8][NJ] = {};
  for (int k0=0; k0<Kn; k0+=16){
    __syncthreads();
    const bool more = (k0+16 < Kn);
    if (more){
      a0 = *(const float4*)(Arow + k0+16);
      a1 = *(const float4*)(Arow + k0+20);
      b0 = *(const float4*)(Wrow + (size_t)(k0+16)*ldB);
      if (TN==128) b1 = *(const float4*)(Wrow + (size_t)(k0+16)*ldB + 4);
    }
#pragma unroll
    for (int kk=0;kk<16;kk++){
      float av[8], bv[NJ];
      *(float4*)&av[0] = *(const float4*)&As[kk][ty<<3];
      *(float4*)&av[4] = *(const float4*)&As[kk][(ty<<3)+4];
      *(float4*)&bv[0] = *(const float4*)&Bs[kk][tx<<2];
      if (TN==128) *(float4*)&bv[4] = *(const float4*)&Bs[kk][64+(tx<<2)];
#pragma unroll
      for(int i=0;i<8;i++)
#pragma unroll
        for(int j=0;j<NJ;j++) acc[i][j] += av[i]*bv[j];
    }
    __syncthreads();
    if (more){
      const int kk0 = ah<<3;
      As[kk0+0][arow]=a0.x; As[kk0+1][arow]=a0.y; As[kk0+2][arow]=a0.z; As[kk0+3][arow]=a0.w;
      As[kk0+4][arow]=a1.x; As[kk0+5][arow]=a1.y; As[kk0+6][arow]=a1.z; As[kk0+7][arow]=a1.w;
      *(float4*)&Bs[brow][bc] = b0;
      if (TN==128) *(float4*)&Bs[brow][bc+4] = b1;
    }
  }
  const int c0 = bn + (tx<<2), c1 = c0 + 64;
  float4 bias0 = make_float4(0,0,0,0), bias1 = make_float4(0,0,0,0);
  if (bias){
    bias0 = *(const float4*)&bias[c0];
    if (TN==128) bias1 = *(const float4*)&bias[c1];
  }
#pragma unroll
  for(int i=0;i<8;i++){
    const int row = bm + (ty<<3) + i;
    {
      float v[NJ];
      v[0]=acc[i][0]+bias0.x; v[1]=acc[i][1]+bias0.y; v[2]=acc[i][2]+bias0.z; v[3]=acc[i][3]+bias0.w;
      if (TN==128){ v[4]=acc[i][4]+bias1.x; v[5]=acc[i][5]+bias1.y; v[6]=acc[i][6]+bias1.z; v[7]=acc[i][7]+bias1.w; }
#pragma unroll
      for(int j=0;j<NJ;j++){
        if (ACT==1) v[j] = tanhf(v[j]);
      }
      float* p0 = Cout + (size_t)row*ldC + c0;
      float4 w0 = make_float4(v[0],v[1],v[2],v[3]);
      if (ACCUM){
        float4 o0 = *(const float4*)p0;
        w0.x+=o0.x; w0.y+=o0.y; w0.z+=o0.z; w0.w+=o0.w;
      }
      *(float4*)p0 = w0;
      if (TN==128){
        float* p1 = Cout + (size_t)row*ldC + c1;
        float4 w1 = make_float4(v[4],v[5],v[6],v[7]);
        if (ACCUM){
          float4 o1 = *(const float4*)p1;
          w1.x+=o1.x; w1.y+=o1.y; w1.z+=o1.z; w1.w+=o1.w;
        }
        *(float4*)p1 = w1;
      }
    }
  }
}

// ---------------- weight split+transpose: W[K][N] fp32 -> WhT/WlT [N][K] f16 ----------------
__global__ __launch_bounds__(256) void k_wsplit(const float* __restrict__ W,
    f16* __restrict__ WhT, f16* __restrict__ WlT, int Kn, int Nn){
  __shared__ float s[32][33];
  const size_t ofs = (size_t)blockIdx.z*Kn*Nn;
  const float* Wb = W + ofs;
  f16* Th = WhT + ofs;
  f16* Tl = WlT + ofs;
  int k0 = (int)blockIdx.x<<5, n0 = (int)blockIdx.y<<5;
  int t = threadIdx.x;
  int r = t>>3, c4 = (t&7)<<2;
  float4 v = *(const float4*)(Wb + (size_t)(k0+r)*Nn + n0 + c4);
  s[r][c4+0]=v.x; s[r][c4+1]=v.y; s[r][c4+2]=v.z; s[r][c4+3]=v.w;
  __syncthreads();
  f16x4 hv, lv;
#pragma unroll
  for(int i=0;i<4;i++){
    float f = s[c4+i][r];
    f16 hh = (f16)f;
    hv[i] = hh;
    lv[i] = (f16)(f - (float)hh);
  }
  *(f16x4*)(Th + (size_t)(n0+r)*Kn + k0 + c4) = hv;
  *(f16x4*)(Tl + (size_t)(n0+r)*Kn + k0 + c4) = lv;
}

// ---------------- MoE MFMA GEMM: fp16-split 3-pass, 128x128 tile, 4 waves ----------------
// D = A*B with A,B split as hi+lo fp16: acc += Ah*Bh + Ah*Bl + Al*Bh  (err ~2^-22)
// MODE 0: e1 — A = h fp32 (gathered via ridx, split in staging), gelu(+bias), out he f16 pair
// MODE 1: e2 first chunk — A = he pair, +bias, store ye fp32
// MODE 2: e2 later chunk — A = he pair, accumulate ye fp32
template<int MODE>
__global__ __launch_bounds__(256) void k_moe_mfma(
    const float* __restrict__ Af,
    const f16* __restrict__ Ah16, const f16* __restrict__ Al16,
    const f16* __restrict__ WhT, const f16* __restrict__ WlT,
    const float* __restrict__ bias,
    const int* __restrict__ ridx, const int* __restrict__ cnt,
    size_t sW, size_t sB,
    f16* __restrict__ Oh, f16* __restrict__ Ol, float* __restrict__ Of,
    int Kn, int ldA, int ldW, int ldC)
{
  const int z = (int)blockIdx.z;
  int Mn = 0, eb = 0;
#pragma unroll
  for(int i=0;i<NE;i++){ int ci = cnt[i]; if (i<z) eb += ci; if (i==z) Mn = ci; }
  const int bm = (int)blockIdx.y<<7, bn = (int)blockIdx.x<<7;
  if (bm >= Mn) return;
  const f16* Wh = WhT + (size_t)z*sW;
  const f16* Wl = WlT + (size_t)z*sW;
  const float* bz = bias ? (bias + (size_t)z*sB) : nullptr;

  __shared__ f16 AhS[128][40];   // [row][k] pad 40 halves (80B rows, 16B aligned)
  __shared__ f16 AlS[128][40];
  __shared__ f16 BhS[128][40];   // [col][k]
  __shared__ f16 BlS[128][40];

  const int tid = threadIdx.x;
  const int lane = tid & 63, wave = tid >> 6;
  const int srow = tid >> 1, sh2 = tid & 1;    // staging: 2 thr per row/col, 16 k each
  int r0 = bm + srow; if (r0 >= Mn) r0 = Mn - 1;
  const int agr = (MODE==0) ? ridx[(size_t)z*NT + r0] : (eb + r0);
  const float* As_f = (MODE==0) ? (Af + (size_t)agr*ldA + (sh2<<4)) : nullptr;
  const f16*   As_h = (MODE!=0) ? (Ah16 + (size_t)agr*ldA + (sh2<<4)) : nullptr;
  const f16*   As_l = (MODE!=0) ? (Al16 + (size_t)agr*ldA + (sh2<<4)) : nullptr;
  const f16*   Bs_h = Wh + (size_t)(bn + srow)*ldW + (sh2<<4);
  const f16*   Bs_l = Wl + (size_t)(bn + srow)*ldW + (sh2<<4);

  const int wr = (wave>>1)<<6, wc = (wave&1)<<6;
  const int l15 = lane & 15, koff = (lane>>4)<<3;
  f32x4 acc[4][4] = {};
  const int T = Kn >> 5;
  for (int t=0; t<T; t++){
    const int k0 = t<<5;
    __syncthreads();                       // WAR: previous frag reads complete
    // ---- stage A ----
    if (MODE==0){
      float fv[16];
      *(float4*)&fv[0]  = *(const float4*)(As_f + k0);
      *(float4*)&fv[4]  = *(const float4*)(As_f + k0 + 4);
      *(float4*)&fv[8]  = *(const float4*)(As_f + k0 + 8);
      *(float4*)&fv[12] = *(const float4*)(As_f + k0 + 12);
      f16x8 vh0, vh1, vl0, vl1;
#pragma unroll
      for(int i=0;i<8;i++){
        f16 h0 = (f16)fv[i];   vh0[i]=h0; vl0[i]=(f16)(fv[i]  -(float)h0);
        f16 h1 = (f16)fv[8+i]; vh1[i]=h1; vl1[i]=(f16)(fv[8+i]-(float)h1);
      }
      *(f16x8*)&AhS[srow][sh2<<4]       = vh0;
      *(f16x8*)&AhS[srow][(sh2<<4)+8]   = vh1;
      *(f16x8*)&AlS[srow][sh2<<4]       = vl0;
      *(f16x8*)&AlS[srow][(sh2<<4)+8]   = vl1;
    } else {
      f16x8 va0 = *(const f16x8*)(As_h + k0);
      f16x8 va1 = *(const f16x8*)(As_h + k0 + 8);
      f16x8 vb0 = *(const f16x8*)(As_l + k0);
      f16x8 vb1 = *(const f16x8*)(As_l + k0 + 8);
      *(f16x8*)&AhS[srow][sh2<<4]     = va0;
      *(f16x8*)&AhS[srow][(sh2<<4)+8] = va1;
      *(f16x8*)&AlS[srow][sh2<<4]     = vb0;
      *(f16x8*)&AlS[srow][(sh2<<4)+8] = vb1;
    }
    // ---- stage B (pre-split, [col][k]) ----
    {
      f16x8 wh0 = *(const f16x8*)(Bs_h + k0);
      f16x8 wh1 = *(const f16x8*)(Bs_h + k0 + 8);
      f16x8 wl0 = *(const f16x8*)(Bs_l + k0);
      f16x8 wl1 = *(const f16x8*)(Bs_l + k0 + 8);
      *(f16x8*)&BhS[srow][sh2<<4]     = wh0;
      *(f16x8*)&BhS[srow][(sh2<<4)+8] = wh1;
      *(f16x8*)&BlS[srow][sh2<<4]     = wl0;
      *(f16x8*)&BlS[srow][(sh2<<4)+8] = wl1;
    }
    __syncthreads();                       // staged tile visible
    // ---- fragments + 3-pass MFMA ----
    f16x8 fah[4], fal[4], fbh[4], fbl[4];
#pragma unroll
    for(int m=0;m<4;m++){
      fah[m] = *(const f16x8*)&AhS[wr + (m<<4) + l15][koff];
      fal[m] = *(const f16x8*)&AlS[wr + (m<<4) + l15][koff];
    }
#pragma unroll
    for(int n=0;n<4;n++){
      fbh[n] = *(const f16x8*)&BhS[wc + (n<<4) + l15][koff];
      fbl[n] = *(const f16x8*)&BlS[wc + (n<<4) + l15][koff];
    }
#pragma unroll
    for(int m=0;m<4;m++)
#pragma unroll
      for(int n=0;n<4;n++){
        acc[m][n] = __builtin_amdgcn_mfma_f32_16x16x32_f16(fah[m], fbh[n], acc[m][n], 0,0,0);
        acc[m][n] = __builtin_amdgcn_mfma_f32_16x16x32_f16(fah[m], fbl[n], acc[m][n], 0,0,0);
        acc[m][n] = __builtin_amdgcn_mfma_f32_16x16x32_f16(fal[m], fbh[n], acc[m][n], 0,0,0);
      }
  }
  // ---- epilogue: C/D layout col=lane&15, row=(lane>>4)*4+reg ----
  const int r4 = (lane>>4)<<2;
#pragma unroll
  for(int m=0;m<4;m++){
#pragma unroll
    for(int n=0;n<4;n++){
      const int col = bn + wc + (n<<4) + l15;
#pragma unroll
      for(int rr=0;rr<4;rr++){
        const int row = bm + wr + (m<<4) + r4 + rr;
        if (row < Mn){
          float val = acc[m][n][rr];
          if (MODE==0){
            val += bz[col];
            val = 0.5f*val*(1.0f+erff(val*0.70710678118654752f));
            f16 hh = (f16)val;
            Oh[(size_t)(eb+row)*ldC + col] = hh;
            Ol[(size_t)(eb+row)*ldC + col] = (f16)(val - (float)hh);
          } else {
            if (MODE==1) val += bz[col];
            float* pp = Of + (size_t)(eb+row)*ldC + col;
            if (MODE==2) *pp += val; else *pp = val;
          }
        }
      }
    }
  }
}

// ---------------- attention: block per (b,head); lane-per-query 1-pass flash ----------------
__global__ __launch_bounds__(256) void k_attn(const float* __restrict__ qkv,
    const float* __restrict__ mem, const float* __restrict__ gate,
    float* __restrict__ y){
  __shared__ float ks[KV*50];
  __shared__ float vs[KV*50];
  const int b = blockIdx.x >> 3, hh = blockIdx.x & 7;
  const int tid = threadIdx.x;
  for(int idx=tid; idx<KV*24; idx+=256){
    int j = idx/24, f = (idx - j*24)*2;
    float2 kvv, vvv;
    if (j < MM){
      kvv = *(const float2*)(mem + j*C + hh*HD + f);
      vvv = kvv;
    } else {
      const float* row = qkv + (size_t)(b*TT + j - MM)*N3C + hh*HD + f;
      kvv = *(const float2*)(row + C);
      vvv = *(const float2*)(row + 2*C);
    }
    *(float2*)(ks + j*50 + f) = kvv;
    *(float2*)(vs + j*50 + f) = vvv;
  }
  __syncthreads();
  const int i = tid;
  const float* qrow = qkv + (size_t)(b*TT+i)*N3C + hh*HD;
  float q[HD];
#pragma unroll
  for(int d2=0; d2<24; d2++){
    float2 qv = *(const float2*)(qrow + d2*2);
    q[d2*2] = qv.x; q[d2*2+1] = qv.y;
  }
  float m = -1e30f, l = 0.f;
  float acc[HD];
#pragma unroll
  for(int d=0;d<HD;d++) acc[d]=0.f;

#define ATT_STEP(JROW) {                                            \
    const float* kr = ks + (JROW)*50;                               \
    float dot = 0.f;                                                \
    _Pragma("unroll")                                               \
    for(int d2=0; d2<24; d2++){                                     \
      float2 kv2 = *(const float2*)(kr + d2*2);                     \
      dot += q[d2*2]*kv2.x + q[d2*2+1]*kv2.y;                       \
    }                                                               \
    float s = dot*SCALE_QK;                                         \
    if (s > m + 8.f){                                               \
      float f_ = __expf(m - s);                                     \
      l *= f_;                                                      \
      _Pragma("unroll")                                             \
      for(int d=0; d<HD; d++) acc[d] *= f_;                         \
      m = s;                                                        \
    }                                                               \
    float pch = __expf(s - m);                                      \
    l += pch;                                                       \
    const float* vr = vs + (JROW)*50;                               \
    _Pragma("unroll")                                               \
    for(int d2=0; d2<24; d2++){                                     \
      float2 vv2 = *(const float2*)(vr + d2*2);                     \
      acc[d2*2]   += pch*vv2.x;                                     \
      acc[d2*2+1] += pch*vv2.y;                                     \
    }                                                               \
  }

  for(int j=0; j<MM; j++) ATT_STEP(j)
  const int lo = (i > WIN) ? (i - WIN) : 0;
  for(int j=MM+lo; j<=MM+i; j++) ATT_STEP(j)
#undef ATT_STEP

  const float inv = 1.f/l;
  const float* g = gate + hh*HD;
  float* yr = y + (size_t)(b*TT+i)*C + hh*HD;
#pragma unroll
  for(int d=0;d<HD;d++) yr[d] = acc[d]*inv*g[d];
}

// ---------------- router ----------------
__global__ void k_gate(const float* __restrict__ h2, const float* __restrict__ gw,
                       const float* __restrict__ gb, float* __restrict__ wout){
  int row = blockIdx.x*4 + (threadIdx.x>>6);
  int lane = threadIdx.x & 63;
  const float* hr = h2 + (size_t)row*C;
  float a0=0,a1=0,a2=0,a3=0;
  for(int c=lane;c<C;c+=64){
    float hv = hr[c];
    const float* g = gw + c*NE;
    a0+=hv*g[0]; a1+=hv*g[1]; a2+=hv*g[2]; a3+=hv*g[3];
  }
  a0=wsum(a0); a1=wsum(a1); a2=wsum(a2); a3=wsum(a3);
  if (lane==0){
    float p[4]={a0+gb[0],a1+gb[1],a2+gb[2],a3+gb[3]};
    float m = fmaxf(fmaxf(p[0],p[1]),fmaxf(p[2],p[3]));
    float s=0.f;
#pragma unroll
    for(int e=0;e<4;e++){ p[e]=expf(p[e]-m); s+=p[e]; }
#pragma unroll
    for(int e=0;e<4;e++) p[e] /= s;
    int i1=0;
    for(int e=1;e<4;e++) if(p[e]>p[i1]) i1=e;
    int i2=-1;
    for(int e=0;e<4;e++){ if(e==i1) continue; if(i2<0 || p[e]>p[i2]) i2=e; }
    float invs = 1.f/(p[i1]+p[i2]+1e-9f);
    float wv[4]={0.f,0.f,0.f,0.f};
    wv[i1]=p[i1]*invs; wv[i2]=p[i2]*invs;
    float* o = wout + (size_t)row*NE;
    o[0]=wv[0]; o[1]=wv[1]; o[2]=wv[2]; o[3]=wv[3];
  }
}

// ---------------- per-expert compaction + inverse map ----------------
__global__ __launch_bounds__(256) void k_compact(const float* __restrict__ wbuf,
    int* __restrict__ ridx, int* __restrict__ posmap, int* __restrict__ cnt){
  int e = blockIdx.x;
  int tid = threadIdx.x;
  int wave = tid>>6, lane = tid&63;
  __shared__ int wsum_s[4];
  __shared__ int base_s;
  if (tid==0) base_s = 0;
  __syncthreads();
  for(int t0=0; t0<NT; t0+=256){
    int t = t0 + tid;
    bool f = wbuf[(size_t)t*NE + e] > 0.f;
    unsigned long long bal = __ballot(f);
    int pre = __popcll(bal & ((1ull<<lane)-1ull));
    if (lane==0) wsum_s[wave] = __popcll(bal);
    __syncthreads();
    int off = 0;
#pragma unroll
    for(int w2=0;w2<4;w2++) if (w2 < wave) off += wsum_s[w2];
    int tot = wsum_s[0]+wsum_s[1]+wsum_s[2]+wsum_s[3];
    int b0 = base_s;
    int pos = b0 + off + pre;
    if (f) ridx[(size_t)e*NT + pos] = t;
    posmap[(size_t)t*NE + e] = f ? pos : -1;
    __syncthreads();
    if (tid==0) base_s = b0 + tot;
    __syncthreads();
  }
  if (tid==0) cnt[e] = base_s;
}

// ---------------- MoE gather: x[t] += sum_e w[t,e] * ye[ebase[e]+pos(t,e)] ----------------
__global__ __launch_bounds__(256) void k_moe_gather(const float* __restrict__ ye,
    const float* __restrict__ wbuf, const int* __restrict__ posmap,
    const int* __restrict__ cnt, float* __restrict__ x){
  int idx = blockIdx.x*256 + threadIdx.x;
  if (idx >= NT*(C/4)) return;
  int eb[NE]; int s=0;
#pragma unroll
  for(int e=0;e<NE;e++){ eb[e]=s; s+=cnt[e]; }
  int t = idx/(C/4), c4 = (idx - t*(C/4))*4;
  float4 acc = *(const float4*)(x + (size_t)t*C + c4);
#pragma unroll
  for(int e=0;e<NE;e++){
    int p = posmap[(size_t)t*NE + e];
    if (p >= 0){
      float w = wbuf[(size_t)t*NE + e];
      float4 yv = *(const float4*)(ye + (size_t)(eb[e]+p)*C + c4);
      acc.x += w*yv.x; acc.y += w*yv.y; acc.z += w*yv.z; acc.w += w*yv.w;
    }
  }
  *(float4*)(x + (size_t)t*C + c4) = acc;
}

extern "C" void kernel_launch(void* const* d_in, const int* in_sizes, int n_in,
                              void* d_out, int out_size, void* d_ws, size_t ws_size,
                              hipStream_t stream){
  (void)in_sizes; (void)n_in; (void)out_size; (void)ws_size;
  const int*   tokens  = (const int*)d_in[0];
  const float* tok_emb = (const float*)d_in[1];
  const float* pos_emb = (const float*)d_in[2];
  const float* mem     = (const float*)d_in[3];
  const float* ln1_w   = (const float*)d_in[4];
  const float* ln1_b   = (const float*)d_in[5];
  const float* qkv_w   = (const float*)d_in[6];
  const float* qkv_b   = (const float*)d_in[7];
  const float* proj_w  = (const float*)d_in[8];
  const float* proj_b  = (const float*)d_in[9];
  const float* attn_g  = (const float*)d_in[10];
  const float* th1_w   = (const float*)d_in[11];
  const float* th1_b   = (const float*)d_in[12];
  const float* th2_w   = (const float*)d_in[13];
  const float* th2_b   = (const float*)d_in[14];
  const float* ln2_w   = (const float*)d_in[15];
  const float* ln2_b   = (const float*)d_in[16];
  const float* gate_w  = (const float*)d_in[17];
  const float* gate_b  = (const float*)d_in[18];
  const float* e1_w    = (const float*)d_in[19];
  const float* e1_b    = (const float*)d_in[20];
  const float* e2_w    = (const float*)d_in[21];
  const float* e2_b    = (const float*)d_in[22];
  const float* lnf_w   = (const float*)d_in[23];
  const float* lnf_b   = (const float*)d_in[24];
  const float* head_w  = (const float*)d_in[25];
  const float* head_b  = (const float*)d_in[26];
  float* out = (float*)d_out;

  char* p = (char*)d_ws;
  float* x    = (float*)p; p += (size_t)NT*C*4;       // residual
  float* h    = (float*)p; p += (size_t)NT*C*4;       // LN out
  char*  rb   = p;                                     // shared region (109 MB)
  float* qkvb = (float*)rb;                            // qkv   [0, 75.5MB)
  float* sh   = (float*)(rb + (size_t)NT*N3C*4);       // y/t1  [75.5, 109MB)
  p += (size_t)NT*N3C*4 + (size_t)NT*TD*4*2;
  float* wbuf = (float*)p; p += (size_t)NT*NE*4;
  int*   ridx = (int*)p;   p += (size_t)NE*NT*4;
  int*   posm = (int*)p;   p += (size_t)NT*NE*4;
  int*   cnt  = (int*)p;   p += 64;
  f16* e1whT = (f16*)p; p += (size_t)NE*FF*C*2;        // weight split buffers (18.9 MB)
  f16* e1wlT = (f16*)p; p += (size_t)NE*FF*C*2;
  f16* e2whT = (f16*)p; p += (size_t)NE*C*FF*2;
  f16* e2wlT = (f16*)p; p += (size_t)NE*C*FF*2;
  // MoE-phase aliases in rb (qkv/sh dead then):
  f16*   heh = (f16*)rb;                               // [0, 25.2MB)
  f16*   hel = (f16*)(rb + (size_t)2*NT*FCH*2);        // [25.2, 50.3MB)
  float* ye  = (float*)(rb + (size_t)2*NT*FCH*4);      // [50.3, 100.6MB)

  dim3 b256(256);
  k_embed<<<dim3((NT*C+255)/256), b256, 0, stream>>>(tokens, tok_emb, pos_emb, x);
  for(int l=0;l<LAYERS;l++){
    k_ln<<<dim3(NT/4), b256, 0, stream>>>(x, ln1_w+l*C, ln1_b+l*C, h);
    k_gemm<0,false,128><<<dim3(N3C/128, NT/128), b256, 0, stream>>>(
        h, qkv_w+(size_t)l*C*N3C, qkv_b+(size_t)l*N3C, qkvb, C, C, N3C, N3C);
    k_attn<<<dim3(BB*NH), b256, 0, stream>>>(qkvb, mem, attn_g+(size_t)l*C, sh);
    k_gemm<0,true,64><<<dim3(C/64, NT/128), b256, 0, stream>>>(
        sh, proj_w+(size_t)l*C*C, proj_b+(size_t)l*C, x, C, C, C, C);
    k_gemm<1,false,64><<<dim3(TD/64, NT/128), b256, 0, stream>>>(
        x, th1_w+(size_t)l*C*TD, th1_b+(size_t)l*TD, sh, C, C, TD, TD);
    k_gemm<0,true,64><<<dim3(C/64, NT/128), b256, 0, stream>>>(
        sh, th2_w+(size_t)l*TD*C, th2_b+(size_t)l*C, x, TD, TD, C, C);
    k_ln<<<dim3(NT/4), b256, 0, stream>>>(x, ln2_w+l*C, ln2_b+l*C, h);
    k_gate<<<dim3(NT/4), b256, 0, stream>>>(h, gate_w+(size_t)l*C*NE, gate_b+(size_t)l*NE, wbuf);
    k_compact<<<dim3(NE), b256, 0, stream>>>(wbuf, ridx, posm, cnt);
    // split+transpose this layer's expert weights (cheap, memory-bound)
    k_wsplit<<<dim3(C/32, FF/32, NE), b256, 0, stream>>>(
        e1_w + (size_t)l*NE*C*FF, e1whT, e1wlT, C, FF);
    k_wsplit<<<dim3(FF/32, C/32, NE), b256, 0, stream>>>(
        e2_w + (size_t)l*NE*FF*C, e2whT, e2wlT, FF, C);
    for(int f0=0; f0<FF; f0+=FCH){
      // he = gelu(h[sel] @ e1[:, f0:f0+FCH] + e1_b) -> f16 hi/lo pair
      k_moe_mfma<0><<<dim3(FCH/128, NT/128, NE), b256, 0, stream>>>(
          h, nullptr, nullptr,
          e1whT + (size_t)f0*C, e1wlT + (size_t)f0*C,
          e1_b + (size_t)l*NE*FF + f0,
          ridx, cnt, (size_t)FF*C, (size_t)FF,
          heh, hel, nullptr, C, C, C, FCH);
      // ye (+)= he @ e2[f0:f0+FCH, :] (+ e2_b on first chunk)
      if (f0==0)
        k_moe_mfma<1><<<dim3(C/128, NT/128, NE), b256, 0, stream>>>(
            nullptr, heh, hel,
            e2whT + f0, e2wlT + f0,
            e2_b + (size_t)l*NE*C,
            ridx, cnt, (size_t)C*FF, (size_t)C,
            nullptr, nullptr, ye, FCH, FCH, FF, C);
      else
        k_moe_mfma<2><<<dim3(C/128, NT/128, NE), b256, 0, stream>>>(
            nullptr, heh, hel,
            e2whT + f0, e2wlT + f0,
            nullptr,
            ridx, cnt, (size_t)C*FF, (size_t)C,
            nullptr, nullptr, ye, FCH, FCH, FF, C);
    }
    k_moe_gather<<<dim3((NT*(C/4)+255)/256), b256, 0, stream>>>(ye, wbuf, posm, cnt, x);
  }
  k_ln<<<dim3(NT/4), b256, 0, stream>>>(x, lnf_w, lnf_b, h);
  k_gemm<0,false,64><<<dim3(NV/64, NT/128), b256, 0, stream>>>(
      h, head_w, head_b, out, C, C, NV, NV);
}

// Round 13
// 9266.361 us; speedup vs baseline: 23.9150x; 1.0855x over previous
//
#include <hip/hip_runtime.h>
#include <math.h>

#define LAYERS 8
#define C 384
#define NH 8
#define NE 4
#define TD 256
#define NV 256
#define WIN 64
#define MM 56
#define HD 48
#define BB 64
#define TT 256
#define NT (BB*TT)
#define N3C 1152
#define FF 1536
#define KV 312
#define FCH 384
#define SCALE_QK 0.14433756729740643f

typedef _Float16 f16;
typedef __attribute__((ext_vector_type(8))) _Float16 f16x8;
typedef __attribute__((ext_vector_type(4))) _Float16 f16x4;
typedef __attribute__((ext_vector_type(4))) float f32x4;

static __device__ __forceinline__ float wsum(float v){
#pragma unroll
  for(int o=32;o;o>>=1) v += __shfl_xor(v,o);
  return v;
}

// ---------------- embed ----------------
__global__ void k_embed(const int* __restrict__ tokens, const float* __restrict__ tok_emb,
                        const float* __restrict__ pos_emb, float* __restrict__ x){
  int idx = blockIdx.x*256 + threadIdx.x;
  if (idx >= NT*C) return;
  int t = idx / C, c = idx - t*C;
  x[idx] = tok_emb[tokens[t]*C + c] + pos_emb[(t % TT)*C + c];
}

// ---------------- layernorm: PAIR -> f16 hi/lo planes, else fp32 ----------------
template<bool PAIR>
__global__ void k_ln(const float* __restrict__ in, const float* __restrict__ w,
                     const float* __restrict__ b, float* __restrict__ outf,
                     f16* __restrict__ oh, f16* __restrict__ ol){
  int row = blockIdx.x*4 + (threadIdx.x>>6);
  int lane = threadIdx.x & 63;
  const float* xr = in + (size_t)row*C;
  float v[6]; float s = 0.f;
#pragma unroll
  for(int i=0;i<6;i++){ v[i]=xr[lane+64*i]; s+=v[i]; }
  s = wsum(s);
  float mu = s*(1.f/C);
  float q=0.f;
#pragma unroll
  for(int i=0;i<6;i++){ float d=v[i]-mu; q+=d*d; }
  q = wsum(q);
  float inv = rsqrtf(q*(1.f/C)+1e-5f);
#pragma unroll
  for(int i=0;i<6;i++){
    int c = lane+64*i;
    float o = (v[i]-mu)*inv*w[c]+b[c];
    size_t oi = (size_t)row*C + c;
    if (PAIR){
      f16 hh = (f16)o;
      oh[oi] = hh;
      ol[oi] = (f16)(o - (float)hh);
    } else {
      outf[oi] = o;
    }
  }
}

// ---------------- fp32 GEMM 128x64 tile (round-6 proven codegen) ----------------
// proj/th1/th2/head. DO NOT: dbuf LDS, raise BK, min-waves, gload_lds (r7-10).
template<int ACT, bool ACCUM>
__global__ __launch_bounds__(256) void k_gemm(
    const float* __restrict__ A, const float* __restrict__ W,
    const float* __restrict__ bias,
    float* __restrict__ Cout, int Kn, int ldA, int ldB, int ldC)
{
  const int bm = (int)blockIdx.y<<7, bn = (int)blockIdx.x*64;
  __shared__ __attribute__((aligned(16))) float As[16][132];
  __shared__ __attribute__((aligned(16))) float Bs[16][68];
  const int tid = threadIdx.x;
  const int tx = tid&15, ty = tid>>4;
  const int arow = tid>>1, ah = tid&1;
  const int brow = tid>>4;
  const int bc = (tid&15)<<2;
  const float* Arow = A + (size_t)(bm+arow)*ldA + (ah<<3);
  const float* Wrow = W + (size_t)brow*ldB + bn + bc;
  float4 a0 = *(const float4*)(Arow);
  float4 a1 = *(const float4*)(Arow+4);
  float4 b0 = *(const float4*)(Wrow);
  {
    const int kk0 = ah<<3;
    As[kk0+0][arow]=a0.x; As[kk0+1][arow]=a0.y; As[kk0+2][arow]=a0.z; As[kk0+3][arow]=a0.w;
    As[kk0+4][arow]=a1.x; As[kk0+5][arow]=a1.y; As[kk0+6][arow]=a1.z; As[kk0+7][arow]=a1.w;
    *(float4*)&Bs[brow][bc] = b0;
  }
  float acc[8][4] = {};
  for (int k0=0; k0<Kn; k0+=16){
    __syncthreads();
    const bool more = (k0+16 < Kn);
    if (more){
      a0 = *(const float4*)(Arow + k0+16);
      a1 = *(const float4*)(Arow + k0+20);
      b0 = *(const float4*)(Wrow + (size_t)(k0+16)*ldB);
    }
#pragma unroll
    for (int kk=0;kk<16;kk++){
      float av[8], bv[4];
      *(float4*)&av[0] = *(const float4*)&As[kk][ty<<3];
      *(float4*)&av[4] = *(const float4*)&As[kk][(ty<<3)+4];
      *(float4*)&bv[0] = *(const float4*)&Bs[kk][tx<<2];
#pragma unroll
      for(int i=0;i<8;i++)
#pragma unroll
        for(int j=0;j<4;j++) acc[i][j] += av[i]*bv[j];
    }
    __syncthreads();
    if (more){
      const int kk0 = ah<<3;
      As[kk0+0][arow]=a0.x; As[kk0+1][arow]=a0.y; As[kk0+2][arow]=a0.z; As[kk0+3][arow]=a0.w;
      As[kk0+4][arow]=a1.x; As[kk0+5][arow]=a1.y; As[kk0+6][arow]=a1.z; As[kk0+7][arow]=a1.w;
      *(float4*)&Bs[brow][bc] = b0;
    }
  }
  const int c0 = bn + (tx<<2);
  float4 bias0 = make_float4(0,0,0,0);
  if (bias) bias0 = *(const float4*)&bias[c0];
#pragma unroll
  for(int i=0;i<8;i++){
    const int row = bm + (ty<<3) + i;
    float v[4];
    v[0]=acc[i][0]+bias0.x; v[1]=acc[i][1]+bias0.y; v[2]=acc[i][2]+bias0.z; v[3]=acc[i][3]+bias0.w;
#pragma unroll
    for(int j=0;j<4;j++){
      if (ACT==1) v[j] = tanhf(v[j]);
    }
    float* p0 = Cout + (size_t)row*ldC + c0;
    float4 w0 = make_float4(v[0],v[1],v[2],v[3]);
    if (ACCUM){
      float4 o0 = *(const float4*)p0;
      w0.x+=o0.x; w0.y+=o0.y; w0.z+=o0.z; w0.w+=o0.w;
    }
    *(float4*)p0 = w0;
  }
}

// ---------------- weight split+transpose: W[K][N] fp32 -> WhT/WlT [N][K] f16 ----------------
__global__ __launch_bounds__(256) void k_wsplit(const float* __restrict__ W,
    f16* __restrict__ WhT, f16* __restrict__ WlT, int Kn, int Nn){
  __shared__ float s[32][33];
  const size_t ofs = (size_t)blockIdx.z*Kn*Nn;
  const float* Wb = W + ofs;
  f16* Th = WhT + ofs;
  f16* Tl = WlT + ofs;
  int k0 = (int)blockIdx.x<<5, n0 = (int)blockIdx.y<<5;
  int t = threadIdx.x;
  int r = t>>3, c4 = (t&7)<<2;
  float4 v = *(const float4*)(Wb + (size_t)(k0+r)*Nn + n0 + c4);
  s[r][c4+0]=v.x; s[r][c4+1]=v.y; s[r][c4+2]=v.z; s[r][c4+3]=v.w;
  __syncthreads();
  f16x4 hv, lv;
#pragma unroll
  for(int i=0;i<4;i++){
    float f = s[c4+i][r];
    f16 hh = (f16)f;
    hv[i] = hh;
    lv[i] = (f16)(f - (float)hh);
  }
  *(f16x4*)(Th + (size_t)(n0+r)*Kn + k0 + c4) = hv;
  *(f16x4*)(Tl + (size_t)(n0+r)*Kn + k0 + c4) = lv;
}

// ---------------- pair-A MFMA GEMM: fp16-split 3-pass, 128x128 tile, 4 waves ----------------
// D = A*B, A/B split hi+lo f16: acc += Ah*Bh + Ah*Bl + Al*Bh  (rel err ~2^-22).
// EPI 0: Of = val (+bias)     (qkv dense, e2 first chunk)
// EPI 1: Of += val            (e2 later chunks)
// EPI 2: gelu(val+bias) -> pair Oh/Ol   (e1)
// MOE: blockIdx.z = expert (cnt/eb); GATHER: A rows via ridx.
template<int EPI, bool MOE, bool GATHER>
__global__ __launch_bounds__(256) void k_mfma(
    const f16* __restrict__ Ah16, const f16* __restrict__ Al16,
    const f16* __restrict__ WhT, const f16* __restrict__ WlT,
    const float* __restrict__ bias,
    const int* __restrict__ ridx, const int* __restrict__ cnt,
    size_t sW, size_t sB,
    f16* __restrict__ Oh, f16* __restrict__ Ol, float* __restrict__ Of,
    int Kn, int ldA, int ldW, int ldC)
{
  const int z = MOE ? (int)blockIdx.z : 0;
  int Mn = NT, eb = 0;
  if (MOE){
    Mn = 0;
#pragma unroll
    for(int i=0;i<NE;i++){ int ci = cnt[i]; if (i<z) eb += ci; if (i==z) Mn = ci; }
  }
  const int bm = (int)blockIdx.y<<7, bn = (int)blockIdx.x<<7;
  if (bm >= Mn) return;
  const f16* Wh = WhT + (MOE ? (size_t)z*sW : 0);
  const f16* Wl = WlT + (MOE ? (size_t)z*sW : 0);
  const float* bz = bias ? (bias + (MOE ? (size_t)z*sB : 0)) : nullptr;

  __shared__ f16 AhS[128][40];
  __shared__ f16 AlS[128][40];
  __shared__ f16 BhS[128][40];
  __shared__ f16 BlS[128][40];

  const int tid = threadIdx.x;
  const int lane = tid & 63, wave = tid >> 6;
  const int srow = tid >> 1, sh2 = tid & 1;
  int r0 = bm + srow; if (r0 >= Mn) r0 = Mn - 1;
  const int agr = GATHER ? ridx[(size_t)z*NT + r0] : (eb + r0);
  const f16* As_h = Ah16 + (size_t)agr*ldA + (sh2<<4);
  const f16* As_l = Al16 + (size_t)agr*ldA + (sh2<<4);
  const f16* Bs_h = Wh + (size_t)(bn + srow)*ldW + (sh2<<4);
  const f16* Bs_l = Wl + (size_t)(bn + srow)*ldW + (sh2<<4);

  const int wr = (wave>>1)<<6, wc = (wave&1)<<6;
  const int l15 = lane & 15, koff = (lane>>4)<<3;
  f32x4 acc[4][4] = {};
  const int T = Kn >> 5;
  for (int t=0; t<T; t++){
    const int k0 = t<<5;
    __syncthreads();                       // WAR: previous frag reads complete
    {
      f16x8 a0 = *(const f16x8*)(As_h + k0);
      f16x8 a1 = *(const f16x8*)(As_h + k0 + 8);
      f16x8 a2 = *(const f16x8*)(As_l + k0);
      f16x8 a3 = *(const f16x8*)(As_l + k0 + 8);
      f16x8 b0 = *(const f16x8*)(Bs_h + k0);
      f16x8 b1 = *(const f16x8*)(Bs_h + k0 + 8);
      f16x8 b2 = *(const f16x8*)(Bs_l + k0);
      f16x8 b3 = *(const f16x8*)(Bs_l + k0 + 8);
      *(f16x8*)&AhS[srow][sh2<<4]     = a0;
      *(f16x8*)&AhS[srow][(sh2<<4)+8] = a1;
      *(f16x8*)&AlS[srow][sh2<<4]     = a2;
      *(f16x8*)&AlS[srow][(sh2<<4)+8] = a3;
      *(f16x8*)&BhS[srow][sh2<<4]     = b0;
      *(f16x8*)&BhS[srow][(sh2<<4)+8] = b1;
      *(f16x8*)&BlS[srow][sh2<<4]     = b2;
      *(f16x8*)&BlS[srow][(sh2<<4)+8] = b3;
    }
    __syncthreads();                       // staged tile visible
    f16x8 fah[4], fal[4], fbh[4], fbl[4];
#pragma unroll
    for(int m=0;m<4;m++){
      fah[m] = *(const f16x8*)&AhS[wr + (m<<4) + l15][koff];
      fal[m] = *(const f16x8*)&AlS[wr + (m<<4) + l15][koff];
    }
#pragma unroll
    for(int n=0;n<4;n++){
      fbh[n] = *(const f16x8*)&BhS[wc + (n<<4) + l15][koff];
      fbl[n] = *(const f16x8*)&BlS[wc + (n<<4) + l15][koff];
    }
#pragma unroll
    for(int m=0;m<4;m++)
#pragma unroll
      for(int n=0;n<4;n++){
        acc[m][n] = __builtin_amdgcn_mfma_f32_16x16x32_f16(fah[m], fbh[n], acc[m][n], 0,0,0);
        acc[m][n] = __builtin_amdgcn_mfma_f32_16x16x32_f16(fah[m], fbl[n], acc[m][n], 0,0,0);
        acc[m][n] = __builtin_amdgcn_mfma_f32_16x16x32_f16(fal[m], fbh[n], acc[m][n], 0,0,0);
      }
  }
  // epilogue: C/D layout col=lane&15, row=(lane>>4)*4+reg
  const int r4 = (lane>>4)<<2;
#pragma unroll
  for(int m=0;m<4;m++){
#pragma unroll
    for(int n=0;n<4;n++){
      const int col = bn + wc + (n<<4) + l15;
#pragma unroll
      for(int rr=0;rr<4;rr++){
        const int row = bm + wr + (m<<4) + r4 + rr;
        if (row < Mn){
          float val = acc[m][n][rr];
          const size_t o = (size_t)(eb+row)*ldC + col;
          if (EPI==2){
            val += bz[col];
            val = 0.5f*val*(1.0f+erff(val*0.70710678118654752f));
            f16 hh = (f16)val;
            Oh[o] = hh;
            Ol[o] = (f16)(val - (float)hh);
          } else if (EPI==1){
            Of[o] += val;
          } else {
            if (bz) val += bz[col];
            Of[o] = val;
          }
        }
      }
    }
  }
}

// ---------------- attention: block per (b,head); lane-per-query 1-pass flash ----------------
__global__ __launch_bounds__(256) void k_attn(const float* __restrict__ qkv,
    const float* __restrict__ mem, const float* __restrict__ gate,
    float* __restrict__ y){
  __shared__ float ks[KV*50];
  __shared__ float vs[KV*50];
  const int b = blockIdx.x >> 3, hh = blockIdx.x & 7;
  const int tid = threadIdx.x;
  for(int idx=tid; idx<KV*24; idx+=256){
    int j = idx/24, f = (idx - j*24)*2;
    float2 kvv, vvv;
    if (j < MM){
      kvv = *(const float2*)(mem + j*C + hh*HD + f);
      vvv = kvv;
    } else {
      const float* row = qkv + (size_t)(b*TT + j - MM)*N3C + hh*HD + f;
      kvv = *(const float2*)(row + C);
      vvv = *(const float2*)(row + 2*C);
    }
    *(float2*)(ks + j*50 + f) = kvv;
    *(float2*)(vs + j*50 + f) = vvv;
  }
  __syncthreads();
  const int i = tid;
  const float* qrow = qkv + (size_t)(b*TT+i)*N3C + hh*HD;
  float q[HD];
#pragma unroll
  for(int d2=0; d2<24; d2++){
    float2 qv = *(const float2*)(qrow + d2*2);
    q[d2*2] = qv.x; q[d2*2+1] = qv.y;
  }
  float m = -1e30f, l = 0.f;
  float acc[HD];
#pragma unroll
  for(int d=0;d<HD;d++) acc[d]=0.f;

#define ATT_STEP(JROW) {                                            \
    const float* kr = ks + (JROW)*50;                               \
    float dot = 0.f;                                                \
    _Pragma("unroll")                                               \
    for(int d2=0; d2<24; d2++){                                     \
      float2 kv2 = *(const float2*)(kr + d2*2);                     \
      dot += q[d2*2]*kv2.x + q[d2*2+1]*kv2.y;                       \
    }                                                               \
    float s = dot*SCALE_QK;                                         \
    if (s > m + 8.f){                                               \
      float f_ = __expf(m - s);                                     \
      l *= f_;                                                      \
      _Pragma("unroll")                                             \
      for(int d=0; d<HD; d++) acc[d] *= f_;                         \
      m = s;                                                        \
    }                                                               \
    float pch = __expf(s - m);                                      \
    l += pch;                                                       \
    const float* vr = vs + (JROW)*50;                               \
    _Pragma("unroll")                                               \
    for(int d2=0; d2<24; d2++){                                     \
      float2 vv2 = *(const float2*)(vr + d2*2);                     \
      acc[d2*2]   += pch*vv2.x;                                     \
      acc[d2*2+1] += pch*vv2.y;                                     \
    }                                                               \
  }

  for(int j=0; j<MM; j++) ATT_STEP(j)
  const int lo = (i > WIN) ? (i - WIN) : 0;
  for(int j=MM+lo; j<=MM+i; j++) ATT_STEP(j)
#undef ATT_STEP

  const float inv = 1.f/l;
  const float* g = gate + hh*HD;
  float* yr = y + (size_t)(b*TT+i)*C + hh*HD;
#pragma unroll
  for(int d=0;d<HD;d++) yr[d] = acc[d]*inv*g[d];
}

// ---------------- router (reads h2 pair; hi+lo reconstruct, err ~2^-22) ----------------
__global__ void k_gate(const f16* __restrict__ hh2, const f16* __restrict__ hl2,
                       const float* __restrict__ gw,
                       const float* __restrict__ gb, float* __restrict__ wout){
  int row = blockIdx.x*4 + (threadIdx.x>>6);
  int lane = threadIdx.x & 63;
  const f16* hr = hh2 + (size_t)row*C;
  const f16* lr = hl2 + (size_t)row*C;
  float a0=0,a1=0,a2=0,a3=0;
  for(int c=lane;c<C;c+=64){
    float hv = (float)hr[c] + (float)lr[c];
    const float* g = gw + c*NE;
    a0+=hv*g[0]; a1+=hv*g[1]; a2+=hv*g[2]; a3+=hv*g[3];
  }
  a0=wsum(a0); a1=wsum(a1); a2=wsum(a2); a3=wsum(a3);
  if (lane==0){
    float p[4]={a0+gb[0],a1+gb[1],a2+gb[2],a3+gb[3]};
    float m = fmaxf(fmaxf(p[0],p[1]),fmaxf(p[2],p[3]));
    float s=0.f;
#pragma unroll
    for(int e=0;e<4;e++){ p[e]=expf(p[e]-m); s+=p[e]; }
#pragma unroll
    for(int e=0;e<4;e++) p[e] /= s;
    int i1=0;
    for(int e=1;e<4;e++) if(p[e]>p[i1]) i1=e;
    int i2=-1;
    for(int e=0;e<4;e++){ if(e==i1) continue; if(i2<0 || p[e]>p[i2]) i2=e; }
    float invs = 1.f/(p[i1]+p[i2]+1e-9f);
    float wv[4]={0.f,0.f,0.f,0.f};
    wv[i1]=p[i1]*invs; wv[i2]=p[i2]*invs;
    float* o = wout + (size_t)row*NE;
    o[0]=wv[0]; o[1]=wv[1]; o[2]=wv[2]; o[3]=wv[3];
  }
}

// ---------------- per-expert compaction + inverse map ----------------
__global__ __launch_bounds__(256) void k_compact(const float* __restrict__ wbuf,
    int* __restrict__ ridx, int* __restrict__ posmap, int* __restrict__ cnt){
  int e = blockIdx.x;
  int tid = threadIdx.x;
  int wave = tid>>6, lane = tid&63;
  __shared__ int wsum_s[4];
  __shared__ int base_s;
  if (tid==0) base_s = 0;
  __syncthreads();
  for(int t0=0; t0<NT; t0+=256){
    int t = t0 + tid;
    bool f = wbuf[(size_t)t*NE + e] > 0.f;
    unsigned long long bal = __ballot(f);
    int pre = __popcll(bal & ((1ull<<lane)-1ull));
    if (lane==0) wsum_s[wave] = __popcll(bal);
    __syncthreads();
    int off = 0;
#pragma unroll
    for(int w2=0;w2<4;w2++) if (w2 < wave) off += wsum_s[w2];
    int tot = wsum_s[0]+wsum_s[1]+wsum_s[2]+wsum_s[3];
    int b0 = base_s;
    int pos = b0 + off + pre;
    if (f) ridx[(size_t)e*NT + pos] = t;
    posmap[(size_t)t*NE + e] = f ? pos : -1;
    __syncthreads();
    if (tid==0) base_s = b0 + tot;
    __syncthreads();
  }
  if (tid==0) cnt[e] = base_s;
}

// ---------------- MoE gather ----------------
__global__ __launch_bounds__(256) void k_moe_gather(const float* __restrict__ ye,
    const float* __restrict__ wbuf, const int* __restrict__ posmap,
    const int* __restrict__ cnt, float* __restrict__ x){
  int idx = blockIdx.x*256 + threadIdx.x;
  if (idx >= NT*(C/4)) return;
  int eb[NE]; int s=0;
#pragma unroll
  for(int e=0;e<NE;e++){ eb[e]=s; s+=cnt[e]; }
  int t = idx/(C/4), c4 = (idx - t*(C/4))*4;
  float4 acc = *(const float4*)(x + (size_t)t*C + c4);
#pragma unroll
  for(int e=0;e<NE;e++){
    int p = posmap[(size_t)t*NE + e];
    if (p >= 0){
      float w = wbuf[(size_t)t*NE + e];
      float4 yv = *(const float4*)(ye + (size_t)(eb[e]+p)*C + c4);
      acc.x += w*yv.x; acc.y += w*yv.y; acc.z += w*yv.z; acc.w += w*yv.w;
    }
  }
  *(float4*)(x + (size_t)t*C + c4) = acc;
}

extern "C" void kernel_launch(void* const* d_in, const int* in_sizes, int n_in,
                              void* d_out, int out_size, void* d_ws, size_t ws_size,
                              hipStream_t stream){
  (void)in_sizes; (void)n_in; (void)out_size; (void)ws_size;
  const int*   tokens  = (const int*)d_in[0];
  const float* tok_emb = (const float*)d_in[1];
  const float* pos_emb = (const float*)d_in[2];
  const float* mem     = (const float*)d_in[3];
  const float* ln1_w   = (const float*)d_in[4];
  const float* ln1_b   = (const float*)d_in[5];
  const float* qkv_w   = (const float*)d_in[6];
  const float* qkv_b   = (const float*)d_in[7];
  const float* proj_w  = (const float*)d_in[8];
  const float* proj_b  = (const float*)d_in[9];
  const float* attn_g  = (const float*)d_in[10];
  const float* th1_w   = (const float*)d_in[11];
  const float* th1_b   = (const float*)d_in[12];
  const float* th2_w   = (const float*)d_in[13];
  const float* th2_b   = (const float*)d_in[14];
  const float* ln2_w   = (const float*)d_in[15];
  const float* ln2_b   = (const float*)d_in[16];
  const float* gate_w  = (const float*)d_in[17];
  const float* gate_b  = (const float*)d_in[18];
  const float* e1_w    = (const float*)d_in[19];
  const float* e1_b    = (const float*)d_in[20];
  const float* e2_w    = (const float*)d_in[21];
  const float* e2_b    = (const float*)d_in[22];
  const float* lnf_w   = (const float*)d_in[23];
  const float* lnf_b   = (const float*)d_in[24];
  const float* head_w  = (const float*)d_in[25];
  const float* head_b  = (const float*)d_in[26];
  float* out = (float*)d_out;

  char* p = (char*)d_ws;
  float* x   = (float*)p; p += (size_t)NT*C*4;         // residual fp32
  f16* h2ph  = (f16*)p;                                 // ln2 pair (lnf reuses as fp32)
  f16* h2pl  = h2ph + (size_t)NT*C;
  float* hf  = (float*)h2ph;                            // lnf fp32 out (after last MoE)
  p += (size_t)NT*C*4;
  char* rb   = p; p += (size_t)NT*N3C*4 + (size_t)2*NT*TD*4;   // 109.05 MB region
  float* qkvb = (float*)rb;                             // [0, 75.5MB)
  char* shreg = rb + (size_t)NT*N3C*4;                  // [75.5, 109MB), 33.5 MB
  f16* h1ph = (f16*)shreg;                              // ln1 pair (dead after qkv)
  f16* h1pl = h1ph + (size_t)NT*C;
  float* y  = (float*)shreg;                            // attn out (dead after proj)
  float* t1 = (float*)shreg;                            // th1 out (dead after th2)
  // MoE-phase aliases in rb (qkvb + sh dead then):
  size_t hePlane = (size_t)2*NT*FCH*2;                  // 25.17 MB per he plane
  f16* heh = (f16*)rb;
  f16* hel = (f16*)(rb + hePlane);
  float* ye = (float*)(rb + 2*hePlane);                 // 50.3 MB, ends at 100.7 <= 109
  float* wbuf = (float*)p; p += (size_t)NT*NE*4;
  int*   ridx = (int*)p;   p += (size_t)NE*NT*4;
  int*   posm = (int*)p;   p += (size_t)NT*NE*4;
  int*   cnt  = (int*)p;   p += 64;
  f16* qwh  = (f16*)p; p += (size_t)C*N3C*2;            // qkv split (per layer)
  f16* qwl  = (f16*)p; p += (size_t)C*N3C*2;
  f16* e1wh = (f16*)p; p += (size_t)NE*C*FF*2;
  f16* e1wl = (f16*)p; p += (size_t)NE*C*FF*2;
  f16* e2wh = (f16*)p; p += (size_t)NE*C*FF*2;
  f16* e2wl = (f16*)p; p += (size_t)NE*C*FF*2;

  dim3 b256(256);
  k_embed<<<dim3((NT*C+255)/256), b256, 0, stream>>>(tokens, tok_emb, pos_emb, x);
  for(int l=0;l<LAYERS;l++){
    k_ln<true><<<dim3(NT/4), b256, 0, stream>>>(x, ln1_w+l*C, ln1_b+l*C, nullptr, h1ph, h1pl);
    k_wsplit<<<dim3(C/32, N3C/32, 1), b256, 0, stream>>>(
        qkv_w + (size_t)l*C*N3C, qwh, qwl, C, N3C);
    k_mfma<0,false,false><<<dim3(N3C/128, NT/128), b256, 0, stream>>>(
        h1ph, h1pl, qwh, qwl, qkv_b + (size_t)l*N3C,
        nullptr, nullptr, 0, 0,
        nullptr, nullptr, qkvb, C, C, C, N3C);
    k_attn<<<dim3(BB*NH), b256, 0, stream>>>(qkvb, mem, attn_g+(size_t)l*C, y);
    k_gemm<0,true><<<dim3(C/64, NT/128), b256, 0, stream>>>(
        y, proj_w+(size_t)l*C*C, proj_b+(size_t)l*C, x, C, C, C, C);
    k_gemm<1,false><<<dim3(TD/64, NT/128), b256, 0, stream>>>(
        x, th1_w+(size_t)l*C*TD, th1_b+(size_t)l*TD, t1, C, C, TD, TD);
    k_gemm<0,true><<<dim3(C/64, NT/128), b256, 0, stream>>>(
        t1, th2_w+(size_t)l*TD*C, th2_b+(size_t)l*C, x, TD, TD, C, C);
    k_ln<true><<<dim3(NT/4), b256, 0, stream>>>(x, ln2_w+l*C, ln2_b+l*C, nullptr, h2ph, h2pl);
    k_gate<<<dim3(NT/4), b256, 0, stream>>>(h2ph, h2pl,
        gate_w+(size_t)l*C*NE, gate_b+(size_t)l*NE, wbuf);
    k_compact<<<dim3(NE), b256, 0, stream>>>(wbuf, ridx, posm, cnt);
    k_wsplit<<<dim3(C/32, FF/32, NE), b256, 0, stream>>>(
        e1_w + (size_t)l*NE*C*FF, e1wh, e1wl, C, FF);
    k_wsplit<<<dim3(FF/32, C/32, NE), b256, 0, stream>>>(
        e2_w + (size_t)l*NE*FF*C, e2wh, e2wl, FF, C);
    for(int f0=0; f0<FF; f0+=FCH){
      // he = gelu(h2[sel] @ e1[:, f0:f0+FCH] + e1_b) -> f16 pair
      k_mfma<2,true,true><<<dim3(FCH/128, NT/128, NE), b256, 0, stream>>>(
          h2ph, h2pl, e1wh + (size_t)f0*C, e1wl + (size_t)f0*C,
          e1_b + (size_t)l*NE*FF + f0,
          ridx, cnt, (size_t)C*FF, (size_t)FF,
          heh, hel, nullptr, C, C, C, FCH);
      // ye (+)= he @ e2[f0:f0+FCH, :] (+ e2_b on first chunk)
      if (f0==0)
        k_mfma<0,true,false><<<dim3(C/128, NT/128, NE), b256, 0, stream>>>(
            heh, hel, e2wh + f0, e2wl + f0,
            e2_b + (size_t)l*NE*C,
            nullptr, cnt, (size_t)C*FF, (size_t)C,
            nullptr, nullptr, ye, FCH, FCH, FF, C);
      else
        k_mfma<1,true,false><<<dim3(C/128, NT/128, NE), b256, 0, stream>>>(
            heh, hel, e2wh + f0, e2wl + f0,
            nullptr,
            nullptr, cnt, (size_t)C*FF, (size_t)C,
            nullptr, nullptr, ye, FCH, FCH, FF, C);
    }
    k_moe_gather<<<dim3((NT*(C/4)+255)/256), b256, 0, stream>>>(ye, wbuf, posm, cnt, x);
  }
  k_ln<false><<<dim3(NT/4), b256, 0, stream>>>(x, lnf_w, lnf_b, hf, nullptr, nullptr);
  k_gemm<0,false><<<dim3(NV/64, NT/128), b256, 0, stream>>>(
      hf, head_w, head_b, out, C, C, NV, NV);
}